// Round 11
// baseline (6050.328 us; speedup 1.0000x reference)
//
#include <hip/hip_runtime.h>

typedef unsigned short u16;
typedef __attribute__((ext_vector_type(4))) float f32x4;
typedef __attribute__((ext_vector_type(8))) __bf16 bf16x8;
typedef __attribute__((ext_vector_type(8))) u16 u16x8;
typedef __attribute__((ext_vector_type(4))) int i32x4;

#define MFMA(a, b, c) __builtin_amdgcn_mfma_f32_16x16x32_bf16(a, b, c, 0, 0, 0)

__device__ __forceinline__ u16 f2bf(float f) {
  union { float f; unsigned u; } v; v.f = f;
  unsigned r = v.u + 0x7FFFu + ((v.u >> 16) & 1u);
  return (u16)(r >> 16);
}
__device__ __forceinline__ float bf2f(u16 b) {
  union { unsigned u; float f; } v; v.u = ((unsigned)b) << 16; return v.f;
}
__device__ __forceinline__ float sigm(float x) { return 1.f / (1.f + __expf(-x)); }
__device__ __forceinline__ float tanh_(float x) {
  float e = __expf(-2.f * fabsf(x));
  float r = (1.f - e) / (1.f + e);
  return x < 0.f ? -r : r;
}

// ---------------------------------------------------------------------------
__global__ __launch_bounds__(256) void cvt_bf16(const float* __restrict__ src,
                                                u16* __restrict__ dst, int n8) {
  int i = blockIdx.x * 256 + threadIdx.x;
  if (i >= n8) return;
  int e = i * 8;
  u16x8 o;
#pragma unroll
  for (int j = 0; j < 8; ++j) o[j] = f2bf(src[e + j]);
  *(u16x8*)(dst + e) = o;
}

// ---------------------------------------------------------------------------
// wrepack_cat: [Whh | Wih] (f32, each 1536x512) -> fused fragment-ordered bf16
// Wp (3MB/dir): index ((q*32 + kk)*3 + gate)*512 + lane*8 holds
//   kk<16 : Whh[gate*512 + q*16 + ln][kk*32 + ks*8 + e]       (h half)
//   kk>=16: Wih[gate*512 + q*16 + ln][(kk-16)*32 + ks*8 + e]  (x half)
// lane = ks*16 + ln. One wave K-step load = 1KB contiguous per gate.
// ---------------------------------------------------------------------------
__global__ __launch_bounds__(256) void wrepack_cat(const float* __restrict__ Whh,
                                                   const float* __restrict__ Wih,
                                                   u16* __restrict__ Wp) {
  int i = blockIdx.x * 256 + threadIdx.x;  // one u16x8 per thread
  if (i >= 196608) return;
  int q = i / 6144;
  int r1 = i % 6144;
  int kk = r1 / 192;
  int r2 = r1 % 192;
  int g = r2 / 64;
  int r3 = r2 % 64;
  int ks = r3 >> 4, ln = r3 & 15;
  const float* src;
  if (kk < 16)
    src = Whh + (size_t)(g * 512 + q * 16 + ln) * 512 + kk * 32 + ks * 8;
  else
    src = Wih + (size_t)(g * 512 + q * 16 + ln) * 512 + (kk - 16) * 32 + ks * 8;
  u16x8 o;
#pragma unroll
  for (int j = 0; j < 8; ++j) o[j] = f2bf(src[j]);
  *(u16x8*)(Wp + (size_t)i * 8) = o;
}

// ---------------------------------------------------------------------------
// sort_len: counting-sort sample ids by window_len (1..15); order[slot]=sample,
// rank[sample]=slot.
// ---------------------------------------------------------------------------
__global__ __launch_bounds__(1024) void sort_len(const int* __restrict__ wlen,
                                                 int* __restrict__ order,
                                                 int* __restrict__ rank) {
  __shared__ int cnt[16];
  __shared__ int off[16];
  const int tid = threadIdx.x;
  if (tid < 16) cnt[tid] = 0;
  __syncthreads();
  for (int i = tid; i < 8192; i += 1024) atomicAdd(&cnt[wlen[i] - 1], 1);
  __syncthreads();
  if (tid == 0) {
    int run = 0;
#pragma unroll
    for (int b = 0; b < 15; ++b) { off[b] = run; run += cnt[b]; }
  }
  __syncthreads();
  for (int i = tid; i < 8192; i += 1024) {
    int pos = atomicAdd(&off[wlen[i] - 1], 1);
    order[pos] = i;
    rank[i] = pos;
  }
}

// ---------------------------------------------------------------------------
// xgather: win (f32) -> xg bf16 [dir*8+t][slot][512]. Pre-gathered, sorted,
// halved bytes: gru's per-step x-stage becomes ONE dense 64KB copy.
// ---------------------------------------------------------------------------
__global__ __launch_bounds__(256) void xgather(const float* __restrict__ win,
                                               const int* __restrict__ wlen,
                                               const int* __restrict__ rank,
                                               u16* __restrict__ xg) {
  const int s = blockIdx.x;  // sample
  const int tid = threadIdx.x;
  const int wl = wlen[s];
  const int slot = rank[s];
  const int len_f = (wl - 1) / 2 + 1, len_b = wl / 2 + 1;
#pragma unroll
  for (int dt = 0; dt < 16; ++dt) {
    const int dir = dt >> 3, t = dt & 7;
    const int len = dir ? len_b : len_f;
    const int widx = dir ? (6 + len - t) : (8 - len + t);  // always in [0,14]
    const float* src = win + ((size_t)s * 15 + widx) * 512 + tid * 2;
    u16* dst = xg + ((size_t)dt * 8192 + slot) * 512 + tid * 2;
    float2 v = *(const float2*)src;
    *(unsigned*)dst = (unsigned)f2bf(v.x) | ((unsigned)f2bf(v.y) << 16);
  }
}

// ---------------------------------------------------------------------------
// gru_fused v2 -- ROUND-10 FIX: round 9 spilled (WRITE 3.5GB) because a
// 1024-thread block forces 4 waves/SIMD = 128-reg cap while the 4-gate
// epilogue needed 64 acc + frags (~160 regs). Fix: each wave owns 16 cols x
// 32 ROWS (was 64): rh = wave&1 row-half, wc = wave>>1 col-group; 4 N-passes.
// Acc drops to 32 f32/lane; total ~95 regs -> fits, no scratch.
// Fragment-ordered Wp (1KB contiguous/gate/wave-load); x_t from pre-gathered
// bf16 xg (dense 64KB copy); sorted slots; 2 barriers/step; passes 0-2 hold
// h_new in regs, written after BAR_B in pass 3.
// ---------------------------------------------------------------------------
#define LROW 520  // padded LDS row stride (bf16)

__global__ __launch_bounds__(1024)
__attribute__((amdgpu_waves_per_eu(4, 4))) void gru_fused(
    const int* __restrict__ wlen, const int* __restrict__ order,
    const u16* __restrict__ Wp_f, const u16* __restrict__ Wp_b,
    const float* __restrict__ bih_f, const float* __restrict__ bhh_f,
    const float* __restrict__ bih_b, const float* __restrict__ bhh_b,
    const u16* __restrict__ xg, u16* __restrict__ hcat) {
  extern __shared__ char smem[];
  u16* h_s = (u16*)smem;                          // [64][LROW]
  u16* x_s = (u16*)(smem + 64 * LROW * 2);        // [64][LROW]
  int* len_s = (int*)(smem + 2 * 64 * LROW * 2);  // [64]
  int* bmax_s = len_s + 64;

  const int dir = blockIdx.x & 1;
  const int grp = blockIdx.x >> 1;
  const int s0 = grp * 64;
  const u16* W = dir ? Wp_b : Wp_f;
  const float* bih = dir ? bih_b : bih_f;
  const float* bhh = dir ? bhh_b : bhh_f;

  const int tid = threadIdx.x;
  const int wave = tid >> 6;  // 0..15
  const int rh = wave & 1;    // row half (0: rows 0-31, 1: rows 32-63)
  const int wc = wave >> 1;   // col group 0..7
  const int lane = tid & 63;
  const int ln = lane & 15;
  const int ks = lane >> 4;  // 0..3

  // ---- init: zero h, lengths (sorted) + block max ----
  if (tid == 0) *bmax_s = 0;
  for (int i = tid; i < 64 * LROW / 8; i += 1024) ((u16x8*)h_s)[i] = (u16x8)0;
  __syncthreads();
  if (tid < 64) {
    int wl = wlen[order[s0 + tid]];
    int len = dir ? (wl / 2 + 1) : ((wl - 1) / 2 + 1);
    len_s[tid] = len;
    atomicMax(bmax_s, len);
  }
  __syncthreads();
  const int bmax = *bmax_s;

  // ---- biases: one 16-col chunk per (pass, wave-col-group) ----
  float b_r[4], b_z[4], b_xn[4], b_hn[4];
#pragma unroll
  for (int p = 0; p < 4; ++p) {
    int d = (p * 8 + wc) * 16 + ln;
    b_r[p] = bih[d] + bhh[d];
    b_z[p] = bih[512 + d] + bhh[512 + d];
    b_xn[p] = bih[1024 + d];
    b_hn[p] = bhh[1024 + d];
  }

  // x-stage mapping: 16 threads per row, 4 x u16x8 each
  const int xrow = tid >> 4;  // 0..63
  const int xseg = tid & 15;  // 0..15

  for (int t = 0; t < bmax; ++t) {
    // ---- stage x_t: dense 64KB copy from pre-gathered bf16 xg ----
    {
      const u16* src = xg + ((size_t)(dir * 8 + t) * 8192 + s0 + xrow) * 512;
      u16* dst = x_s + xrow * LROW;
#pragma unroll
      for (int i = 0; i < 4; ++i) {
        const int off = xseg * 32 + i * 8;
        *(u16x8*)(dst + off) = *(const u16x8*)(src + off);
      }
    }
    __syncthreads();  // BAR_A: x_t staged, previous h writes visible

    unsigned holdp[3][4];  // passes 0..2: 2 mt x 2 jp packed 2xbf16

#pragma unroll
    for (int p = 0; p < 4; ++p) {
      const int q = p * 8 + wc;  // gate-col chunk 0..31
      const int dcol = q * 16 + ln;
      const u16* wq = W + (size_t)q * 49152 + lane * 8;  // fragment-ordered

      f32x4 accr[2], accz[2], acchn[2], accxn[2];
#pragma unroll
      for (int mt = 0; mt < 2; ++mt)
#pragma unroll
        for (int j = 0; j < 4; ++j) {
          accr[mt][j] = 0.f; accz[mt][j] = 0.f;
          acchn[mt][j] = 0.f; accxn[mt][j] = 0.f;
        }

      // K-loop, h half (kk 0..15): accumulate r, z, hn
#pragma unroll
      for (int kk = 0; kk < 16; ++kk) {
        const int krel = kk * 32 + ks * 8;
        bf16x8 a[2];
#pragma unroll
        for (int mt = 0; mt < 2; ++mt)
          a[mt] = *(const bf16x8*)(h_s + (rh * 32 + mt * 16 + ln) * LROW + krel);
        const u16* wk = wq + kk * 1536;
        bf16x8 br = *(const bf16x8*)(wk);
        bf16x8 bz = *(const bf16x8*)(wk + 512);
        bf16x8 bn = *(const bf16x8*)(wk + 1024);
#pragma unroll
        for (int mt = 0; mt < 2; ++mt) {
          accr[mt] = MFMA(a[mt], br, accr[mt]);
          accz[mt] = MFMA(a[mt], bz, accz[mt]);
          acchn[mt] = MFMA(a[mt], bn, acchn[mt]);
        }
      }
      // K-loop, x half (kk 16..31): accumulate r, z, xn
#pragma unroll
      for (int kk = 0; kk < 16; ++kk) {
        const int krel = kk * 32 + ks * 8;
        bf16x8 a[2];
#pragma unroll
        for (int mt = 0; mt < 2; ++mt)
          a[mt] = *(const bf16x8*)(x_s + (rh * 32 + mt * 16 + ln) * LROW + krel);
        const u16* wk = wq + (16 + kk) * 1536;
        bf16x8 br = *(const bf16x8*)(wk);
        bf16x8 bz = *(const bf16x8*)(wk + 512);
        bf16x8 bn = *(const bf16x8*)(wk + 1024);
#pragma unroll
        for (int mt = 0; mt < 2; ++mt) {
          accr[mt] = MFMA(a[mt], br, accr[mt]);
          accz[mt] = MFMA(a[mt], bz, accz[mt]);
          accxn[mt] = MFMA(a[mt], bn, accxn[mt]);
        }
      }

      if (p < 3) {
        // hold h_new in regs (h_s/x_s still being read by other waves)
#pragma unroll
        for (int mt = 0; mt < 2; ++mt)
#pragma unroll
          for (int jp = 0; jp < 2; ++jp) {
            unsigned pk = 0;
#pragma unroll
            for (int jh = 0; jh < 2; ++jh) {
              const int j = jp * 2 + jh;
              const int row = rh * 32 + mt * 16 + ks * 4 + j;
              float rr = sigm(accr[mt][j] + b_r[p]);
              float zz = sigm(accz[mt][j] + b_z[p]);
              float nn = tanh_(accxn[mt][j] + b_xn[p] +
                               rr * (acchn[mt][j] + b_hn[p]));
              float hold = bf2f(h_s[row * LROW + dcol]);
              float hnew = (t < len_s[row]) ? ((1.f - zz) * nn + zz * hold) : hold;
              pk |= ((unsigned)f2bf(hnew)) << (16 * jh);
            }
            holdp[p][mt * 2 + jp] = pk;
          }
      } else {
        __syncthreads();  // BAR_B: all K-loop reads of h_s/x_s done
        // write held passes 0..2 (chunks wc, 8+wc, 16+wc; disjoint cols/rows)
#pragma unroll
        for (int pp = 0; pp < 3; ++pp) {
          const int dd = (pp * 8 + wc) * 16 + ln;
#pragma unroll
          for (int mt = 0; mt < 2; ++mt)
#pragma unroll
            for (int jp = 0; jp < 2; ++jp) {
              unsigned pk = holdp[pp][mt * 2 + jp];
              const int row = rh * 32 + mt * 16 + ks * 4 + jp * 2;
              h_s[row * LROW + dd] = (u16)pk;
              h_s[(row + 1) * LROW + dd] = (u16)(pk >> 16);
            }
        }
        // pass-3 epilogue: compute and write directly (chunk 24+wc; only this
        // wave writes these cols/rows, h_old there still previous step's)
#pragma unroll
        for (int mt = 0; mt < 2; ++mt)
#pragma unroll
          for (int j = 0; j < 4; ++j) {
            const int row = rh * 32 + mt * 16 + ks * 4 + j;
            float rr = sigm(accr[mt][j] + b_r[3]);
            float zz = sigm(accz[mt][j] + b_z[3]);
            float nn = tanh_(accxn[mt][j] + b_xn[3] +
                             rr * (acchn[mt][j] + b_hn[3]));
            float hold = bf2f(h_s[row * LROW + dcol]);
            float hnew = (t < len_s[row]) ? ((1.f - zz) * nn + zz * hold) : hold;
            h_s[row * LROW + dcol] = f2bf(hnew);
          }
      }
    }  // passes
  }    // t

  __syncthreads();  // final h writes visible
  // ---- write final h to hcat[slot][dir*512 + k] ----
#pragma unroll
  for (int i = 0; i < 4; ++i) {
    int off = (i * 16 + xseg) * 8;
    u16x8 v = *(const u16x8*)(h_s + xrow * LROW + off);
    __builtin_nontemporal_store(
        v, (u16x8*)(hcat + (size_t)(s0 + xrow) * 1024 + dir * 512 + off));
  }
}

// ---------------------------------------------------------------------------
// FALLBACK path (ws too small): round-2 fused kernel (no sort needed).
// ---------------------------------------------------------------------------
__global__ __launch_bounds__(256) void build_wcat(const float* __restrict__ Whh,
                                                  const float* __restrict__ Wih,
                                                  u16* __restrict__ Wcat) {
  int i = blockIdx.x * 256 + threadIdx.x;
  if (i >= 1536 * 1024 / 8) return;
  int e = i * 8;
  int g = e >> 10, k = e & 1023;
  const float* src = (k < 512) ? (Whh + g * 512 + k) : (Wih + g * 512 + (k - 512));
  u16x8 o;
#pragma unroll
  for (int j = 0; j < 8; ++j) o[j] = f2bf(src[j]);
  *(u16x8*)(Wcat + e) = o;
}

__global__ __launch_bounds__(512)
__attribute__((amdgpu_waves_per_eu(2, 2))) void gru_persistent(
    const float* __restrict__ win, const int* __restrict__ wlen,
    const u16* __restrict__ Wcat_f, const u16* __restrict__ Wcat_b,
    const float* __restrict__ bih_f, const float* __restrict__ bhh_f,
    const float* __restrict__ bih_b, const float* __restrict__ bhh_b,
    u16* __restrict__ hcat) {
  extern __shared__ char smem[];
  u16* h_s = (u16*)smem;
  u16* x_s = (u16*)(smem + 64 * LROW * 2);
  int* len_s = (int*)(smem + 2 * 64 * LROW * 2);
  int* bmax_s = len_s + 64;

  const int dir = blockIdx.x & 1;
  const int grp = blockIdx.x >> 1;
  const int s0 = grp * 64;
  const u16* W = dir ? Wcat_b : Wcat_f;
  const float* bih = dir ? bih_b : bih_f;
  const float* bhh = dir ? bhh_b : bhh_f;

  const int tid = threadIdx.x;
  const int wave = tid >> 6;
  const int lane = tid & 63;
  const int ln = lane & 15;
  const int ks = lane >> 4;

  if (tid == 0) *bmax_s = 0;
  for (int i = tid; i < 64 * LROW / 8; i += 512) ((u16x8*)h_s)[i] = (u16x8)0;
  __syncthreads();
  if (tid < 64) {
    int wl = wlen[s0 + tid];
    int len = dir ? (wl / 2 + 1) : ((wl - 1) / 2 + 1);
    len_s[tid] = len;
    atomicMax(bmax_s, len);
  }
  __syncthreads();
  const int bmax = *bmax_s;

  float b_r[4], b_z[4], b_xn[4], b_hn[4];
#pragma unroll
  for (int p = 0; p < 4; ++p) {
    int d = (p * 8 + wave) * 16 + ln;
    b_r[p] = bih[d] + bhh[d];
    b_z[p] = bih[512 + d] + bhh[512 + d];
    b_xn[p] = bih[1024 + d];
    b_hn[p] = bhh[1024 + d];
  }

  const int xrow = tid >> 3;
  const int xcol = tid & 7;
  const int mylen = len_s[xrow];
  const long xbase = (long)(s0 + xrow) * 15 + (dir ? (6 + mylen) : (8 - mylen));

  for (int t = 0; t < bmax; ++t) {
    {
      long rowidx = dir ? (xbase - t) : (xbase + t);
      const float* src = win + rowidx * 512;
      u16* dst = x_s + xrow * LROW;
#pragma unroll
      for (int i = 0; i < 8; ++i) {
        int off = xcol * 8 + i * 64;
        f32x4 v0 = *(const f32x4*)(src + off);
        f32x4 v1 = *(const f32x4*)(src + off + 4);
        u16x8 o;
        o[0] = f2bf(v0[0]); o[1] = f2bf(v0[1]); o[2] = f2bf(v0[2]); o[3] = f2bf(v0[3]);
        o[4] = f2bf(v1[0]); o[5] = f2bf(v1[1]); o[6] = f2bf(v1[2]); o[7] = f2bf(v1[3]);
        *(u16x8*)(dst + off) = o;
      }
    }
    __syncthreads();

    unsigned holdp[3][4][2];

#pragma unroll
    for (int p = 0; p < 4; ++p) {
      const int dcol = (p * 8 + wave) * 16 + ln;
      const u16* wrow = W + (size_t)dcol * 1024;

      f32x4 accr[4], accz[4], acchn[4], accxn[4];
#pragma unroll
      for (int mt = 0; mt < 4; ++mt)
#pragma unroll
        for (int j = 0; j < 4; ++j) {
          accr[mt][j] = 0.f; accz[mt][j] = 0.f;
          acchn[mt][j] = 0.f; accxn[mt][j] = 0.f;
        }

#pragma unroll
      for (int kk = 0; kk < 16; ++kk) {
        const int krel = kk * 32 + ks * 8;
        bf16x8 a[4];
#pragma unroll
        for (int mt = 0; mt < 4; ++mt)
          a[mt] = *(const bf16x8*)(h_s + (mt * 16 + ln) * LROW + krel);
        bf16x8 br = *(const bf16x8*)(wrow + krel);
        bf16x8 bz = *(const bf16x8*)(wrow + 512 * 1024 + krel);
        bf16x8 bn = *(const bf16x8*)(wrow + 1024 * 1024 + krel);
#pragma unroll
        for (int mt = 0; mt < 4; ++mt) {
          accr[mt] = MFMA(a[mt], br, accr[mt]);
          accz[mt] = MFMA(a[mt], bz, accz[mt]);
          acchn[mt] = MFMA(a[mt], bn, acchn[mt]);
        }
      }
#pragma unroll
      for (int kk = 0; kk < 16; ++kk) {
        const int krel = kk * 32 + ks * 8;
        bf16x8 a[4];
#pragma unroll
        for (int mt = 0; mt < 4; ++mt)
          a[mt] = *(const bf16x8*)(x_s + (mt * 16 + ln) * LROW + krel);
        bf16x8 br = *(const bf16x8*)(wrow + 512 + krel);
        bf16x8 bz = *(const bf16x8*)(wrow + 512 * 1024 + 512 + krel);
        bf16x8 bn = *(const bf16x8*)(wrow + 1024 * 1024 + 512 + krel);
#pragma unroll
        for (int mt = 0; mt < 4; ++mt) {
          accr[mt] = MFMA(a[mt], br, accr[mt]);
          accz[mt] = MFMA(a[mt], bz, accz[mt]);
          accxn[mt] = MFMA(a[mt], bn, accxn[mt]);
        }
      }

      if (p < 3) {
#pragma unroll
        for (int mt = 0; mt < 4; ++mt)
#pragma unroll
          for (int jp = 0; jp < 2; ++jp) {
            unsigned pk = 0;
#pragma unroll
            for (int jh = 0; jh < 2; ++jh) {
              const int j = jp * 2 + jh;
              const int row = mt * 16 + ks * 4 + j;
              float rr = sigm(accr[mt][j] + b_r[p]);
              float zz = sigm(accz[mt][j] + b_z[p]);
              float nn = tanh_(accxn[mt][j] + b_xn[p] +
                               rr * (acchn[mt][j] + b_hn[p]));
              float hold = bf2f(h_s[row * LROW + dcol]);
              float hnew = (t < len_s[row]) ? ((1.f - zz) * nn + zz * hold) : hold;
              pk |= ((unsigned)f2bf(hnew)) << (16 * jh);
            }
            holdp[p][mt][jp] = pk;
          }
      } else {
        __syncthreads();
#pragma unroll
        for (int pp = 0; pp < 3; ++pp) {
          const int dd = (pp * 8 + wave) * 16 + ln;
#pragma unroll
          for (int mt = 0; mt < 4; ++mt)
#pragma unroll
            for (int jp = 0; jp < 2; ++jp) {
              unsigned pk = holdp[pp][mt][jp];
              const int row = mt * 16 + ks * 4 + jp * 2;
              h_s[row * LROW + dd] = (u16)pk;
              h_s[(row + 1) * LROW + dd] = (u16)(pk >> 16);
            }
        }
#pragma unroll
        for (int mt = 0; mt < 4; ++mt)
#pragma unroll
          for (int j = 0; j < 4; ++j) {
            const int row = mt * 16 + ks * 4 + j;
            float rr = sigm(accr[mt][j] + b_r[3]);
            float zz = sigm(accz[mt][j] + b_z[3]);
            float nn = tanh_(accxn[mt][j] + b_xn[3] +
                             rr * (acchn[mt][j] + b_hn[3]));
            float hold = bf2f(h_s[row * LROW + dcol]);
            float hnew = (t < len_s[row]) ? ((1.f - zz) * nn + zz * hold) : hold;
            h_s[row * LROW + dcol] = f2bf(hnew);
          }
      }
    }
  }

  __syncthreads();
#pragma unroll
  for (int i = 0; i < 8; ++i) {
    int off = xcol * 8 + i * 64;
    u16x8 v = *(const u16x8*)(h_s + xrow * LROW + off);
    __builtin_nontemporal_store(
        v, (u16x8*)(hcat + (size_t)(s0 + xrow) * 1024 + dir * 512 + off));
  }
}

// ---------------------------------------------------------------------------
// MLP GEMM: out[M,N] = act(A[M,K] @ Bw[N,K]^T + bias)
// perm != nullptr: store row goes to perm[row] (undoes the length sort).
// ---------------------------------------------------------------------------
__global__ __launch_bounds__(256) void mlp_gemm(const u16* __restrict__ A,
                                                const u16* __restrict__ Bw,
                                                const float* __restrict__ bias,
                                                const int* __restrict__ perm,
                                                void* __restrict__ out, int M,
                                                int N, int K, int mode) {
  __shared__ u16 As[128 * 64], Bs[128 * 64];
  const int tid = threadIdx.x;
  const int wave = tid >> 6, lane = tid & 63;
  const int ln = lane & 15, ks = lane >> 4;
  const int wm = wave & 1, wn = wave >> 1;
  const int m0 = blockIdx.x * 128, n0 = blockIdx.y * 128;
  f32x4 acc[4][4];
#pragma unroll
  for (int mt = 0; mt < 4; ++mt)
#pragma unroll
    for (int nt = 0; nt < 4; ++nt)
#pragma unroll
      for (int j = 0; j < 4; ++j) acc[mt][nt][j] = 0.f;

  const int r = tid >> 1, hh = tid & 1;
  for (int k0 = 0; k0 < K; k0 += 64) {
    const i32x4* sa = (const i32x4*)(A + (size_t)(m0 + r) * K + k0 + hh * 32);
    const i32x4* sb = (const i32x4*)(Bw + (size_t)(n0 + r) * K + k0 + hh * 32);
    i32x4* da = (i32x4*)(As + r * 64 + hh * 32);
    i32x4* db = (i32x4*)(Bs + r * 64 + hh * 32);
#pragma unroll
    for (int i = 0; i < 4; ++i) da[i] = sa[i];
#pragma unroll
    for (int i = 0; i < 4; ++i) db[i] = sb[i];
    __syncthreads();
#pragma unroll
    for (int kk = 0; kk < 2; ++kk) {
      bf16x8 af[4], bfm[4];
#pragma unroll
      for (int mt = 0; mt < 4; ++mt)
        af[mt] = *(const bf16x8*)(As + (wm * 64 + mt * 16 + ln) * 64 + kk * 32 + ks * 8);
#pragma unroll
      for (int nt = 0; nt < 4; ++nt)
        bfm[nt] = *(const bf16x8*)(Bs + (wn * 64 + nt * 16 + ln) * 64 + kk * 32 + ks * 8);
#pragma unroll
      for (int mt = 0; mt < 4; ++mt)
#pragma unroll
        for (int nt = 0; nt < 4; ++nt) acc[mt][nt] = MFMA(af[mt], bfm[nt], acc[mt][nt]);
    }
    __syncthreads();
  }

#pragma unroll
  for (int nt = 0; nt < 4; ++nt) {
    int col = n0 + wn * 64 + nt * 16 + ln;
    float bv = bias[col];
#pragma unroll
    for (int mt = 0; mt < 4; ++mt)
#pragma unroll
      for (int j = 0; j < 4; ++j) {
        int row = m0 + wm * 64 + mt * 16 + ks * 4 + j;
        float v = acc[mt][nt][j] + bv;
        int orow = perm ? perm[row] : row;
        if (mode) {
          v = fmaxf(v, 0.f);
          ((u16*)out)[(size_t)orow * N + col] = f2bf(v);
        } else {
          ((float*)out)[(size_t)orow * N + col] = v;
        }
      }
  }
}

// ---------------------------------------------------------------------------
extern "C" void kernel_launch(void* const* d_in, const int* in_sizes, int n_in,
                              void* d_out, int out_size, void* d_ws, size_t ws_size,
                              hipStream_t stream) {
  (void)in_sizes; (void)n_in; (void)out_size;
  const float* win = (const float*)d_in[0];
  const int* wlen = (const int*)d_in[1];
  const float* Wih_f = (const float*)d_in[2];
  const float* Whh_f = (const float*)d_in[3];
  const float* bih_f = (const float*)d_in[4];
  const float* bhh_f = (const float*)d_in[5];
  const float* Wih_b = (const float*)d_in[6];
  const float* Whh_b = (const float*)d_in[7];
  const float* bih_b = (const float*)d_in[8];
  const float* bhh_b = (const float*)d_in[9];
  const float* W1 = (const float*)d_in[10];
  const float* b1 = (const float*)d_in[11];
  const float* W2 = (const float*)d_in[12];
  const float* b2 = (const float*)d_in[13];

  // main path: Wp 2x3MB + W1b + W2b + hcat + hidden + order/rank + xg 128MB
  const size_t NEED = 2ull * 3145728 + 1048576 + 524288 + 16777216 + 8388608 +
                      65536 + 134217728ull;  // = 167,313,408

  if (ws_size >= NEED) {
    char* ws = (char*)d_ws;
    u16* Wp_f = (u16*)ws;   ws += 3145728;
    u16* Wp_b = (u16*)ws;   ws += 3145728;
    u16* W1b = (u16*)ws;    ws += 1048576;
    u16* W2b = (u16*)ws;    ws += 524288;
    u16* hcat = (u16*)ws;   ws += 16777216;
    u16* hidden = (u16*)ws; ws += 8388608;
    int* order = (int*)ws;  ws += 32768;
    int* rank = (int*)ws;   ws += 32768;
    u16* xg = (u16*)ws;     ws += 134217728;

    sort_len<<<1, 1024, 0, stream>>>(wlen, order, rank);
    wrepack_cat<<<768, 256, 0, stream>>>(Whh_f, Wih_f, Wp_f);
    wrepack_cat<<<768, 256, 0, stream>>>(Whh_b, Wih_b, Wp_b);
    cvt_bf16<<<256, 256, 0, stream>>>(W1, W1b, 65536);
    cvt_bf16<<<128, 256, 0, stream>>>(W2, W2b, 32768);

    xgather<<<8192, 256, 0, stream>>>(win, wlen, rank, xg);

    const int SMEM = 2 * 64 * LROW * 2 + 64 * 4 + 16;
    (void)hipFuncSetAttribute((const void*)gru_fused,
                              hipFuncAttributeMaxDynamicSharedMemorySize, SMEM);
    gru_fused<<<256, 1024, SMEM, stream>>>(wlen, order, Wp_f, Wp_b, bih_f,
                                           bhh_f, bih_b, bhh_b, xg, hcat);

    mlp_gemm<<<dim3(64, 4), 256, 0, stream>>>(hcat, W1b, b1, nullptr, hidden,
                                              8192, 512, 1024, 1);
    mlp_gemm<<<dim3(64, 4), 256, 0, stream>>>(hidden, W2b, b2, order, d_out,
                                              8192, 512, 512, 0);
  } else {
    char* ws = (char*)d_ws;
    u16* Wcat_f = (u16*)ws;  ws += 3145728;
    u16* Wcat_b = (u16*)ws;  ws += 3145728;
    u16* W1b = (u16*)ws;     ws += 1048576;
    u16* W2b = (u16*)ws;     ws += 524288;
    u16* hcat = (u16*)ws;    ws += 16777216;
    u16* hidden = (u16*)ws;  ws += 8388608;

    build_wcat<<<768, 256, 0, stream>>>(Whh_f, Wih_f, Wcat_f);
    build_wcat<<<768, 256, 0, stream>>>(Whh_b, Wih_b, Wcat_b);
    cvt_bf16<<<256, 256, 0, stream>>>(W1, W1b, 65536);
    cvt_bf16<<<128, 256, 0, stream>>>(W2, W2b, 32768);

    const int SMEM = 2 * 64 * LROW * 2 + 64 * 4 + 16;
    (void)hipFuncSetAttribute((const void*)gru_persistent,
                              hipFuncAttributeMaxDynamicSharedMemorySize, SMEM);
    gru_persistent<<<256, 512, SMEM, stream>>>(win, wlen, Wcat_f, Wcat_b, bih_f,
                                               bhh_f, bih_b, bhh_b, hcat);

    mlp_gemm<<<dim3(64, 4), 256, 0, stream>>>(hcat, W1b, b1, nullptr, hidden,
                                              8192, 512, 1024, 1);
    mlp_gemm<<<dim3(64, 4), 256, 0, stream>>>(hidden, W2b, b2, nullptr, d_out,
                                              8192, 512, 512, 0);
  }
}

// Round 12
// 3553.773 us; speedup vs baseline: 1.7025x; 1.7025x over previous
//
#include <hip/hip_runtime.h>

typedef unsigned short u16;
typedef __attribute__((ext_vector_type(4))) float f32x4;
typedef __attribute__((ext_vector_type(8))) __bf16 bf16x8;
typedef __attribute__((ext_vector_type(8))) u16 u16x8;
typedef __attribute__((ext_vector_type(4))) int i32x4;

#define MFMA(a, b, c) __builtin_amdgcn_mfma_f32_16x16x32_bf16(a, b, c, 0, 0, 0)

__device__ __forceinline__ u16 f2bf(float f) {
  union { float f; unsigned u; } v; v.f = f;
  unsigned r = v.u + 0x7FFFu + ((v.u >> 16) & 1u);
  return (u16)(r >> 16);
}
__device__ __forceinline__ float bf2f(u16 b) {
  union { unsigned u; float f; } v; v.u = ((unsigned)b) << 16; return v.f;
}
__device__ __forceinline__ float sigm(float x) { return 1.f / (1.f + __expf(-x)); }
__device__ __forceinline__ float tanh_(float x) {
  float e = __expf(-2.f * fabsf(x));
  float r = (1.f - e) / (1.f + e);
  return x < 0.f ? -r : r;
}

// ---------------------------------------------------------------------------
__global__ __launch_bounds__(256) void cvt_bf16(const float* __restrict__ src,
                                                u16* __restrict__ dst, int n8) {
  int i = blockIdx.x * 256 + threadIdx.x;
  if (i >= n8) return;
  int e = i * 8;
  u16x8 o;
#pragma unroll
  for (int j = 0; j < 8; ++j) o[j] = f2bf(src[e + j]);
  *(u16x8*)(dst + e) = o;
}

// ---------------------------------------------------------------------------
// wrepack_cat: [Whh | Wih] (f32, each 1536x512) -> fused fragment-ordered bf16
// Wp (3MB/dir): index ((q*32 + kk)*3 + gate)*512 + lane*8 holds
//   kk<16 : Whh[gate*512 + q*16 + ln][kk*32 + ks*8 + e]       (h half)
//   kk>=16: Wih[gate*512 + q*16 + ln][(kk-16)*32 + ks*8 + e]  (x half)
// lane = ks*16 + ln. One wave K-step load = 1KB contiguous per gate.
// ---------------------------------------------------------------------------
__global__ __launch_bounds__(256) void wrepack_cat(const float* __restrict__ Whh,
                                                   const float* __restrict__ Wih,
                                                   u16* __restrict__ Wp) {
  int i = blockIdx.x * 256 + threadIdx.x;  // one u16x8 per thread
  if (i >= 196608) return;
  int q = i / 6144;
  int r1 = i % 6144;
  int kk = r1 / 192;
  int r2 = r1 % 192;
  int g = r2 / 64;
  int r3 = r2 % 64;
  int ks = r3 >> 4, ln = r3 & 15;
  const float* src;
  if (kk < 16)
    src = Whh + (size_t)(g * 512 + q * 16 + ln) * 512 + kk * 32 + ks * 8;
  else
    src = Wih + (size_t)(g * 512 + q * 16 + ln) * 512 + (kk - 16) * 32 + ks * 8;
  u16x8 o;
#pragma unroll
  for (int j = 0; j < 8; ++j) o[j] = f2bf(src[j]);
  *(u16x8*)(Wp + (size_t)i * 8) = o;
}

// ---------------------------------------------------------------------------
// sort_len: counting-sort sample ids by window_len (1..15); order[slot]=sample,
// rank[sample]=slot.
// ---------------------------------------------------------------------------
__global__ __launch_bounds__(1024) void sort_len(const int* __restrict__ wlen,
                                                 int* __restrict__ order,
                                                 int* __restrict__ rank) {
  __shared__ int cnt[16];
  __shared__ int off[16];
  const int tid = threadIdx.x;
  if (tid < 16) cnt[tid] = 0;
  __syncthreads();
  for (int i = tid; i < 8192; i += 1024) atomicAdd(&cnt[wlen[i] - 1], 1);
  __syncthreads();
  if (tid == 0) {
    int run = 0;
#pragma unroll
    for (int b = 0; b < 15; ++b) { off[b] = run; run += cnt[b]; }
  }
  __syncthreads();
  for (int i = tid; i < 8192; i += 1024) {
    int pos = atomicAdd(&off[wlen[i] - 1], 1);
    order[pos] = i;
    rank[i] = pos;
  }
}

// ---------------------------------------------------------------------------
// xgather: win (f32) -> xg bf16 [dir*8+t][slot][512]. Pre-gathered, sorted.
// Scatter is at 1KB-row granularity on the WRITE side -> dense lines, no RMW.
// ---------------------------------------------------------------------------
__global__ __launch_bounds__(256) void xgather(const float* __restrict__ win,
                                               const int* __restrict__ wlen,
                                               const int* __restrict__ rank,
                                               u16* __restrict__ xg) {
  const int s = blockIdx.x;  // sample
  const int tid = threadIdx.x;
  const int wl = wlen[s];
  const int slot = rank[s];
  const int len_f = (wl - 1) / 2 + 1, len_b = wl / 2 + 1;
#pragma unroll
  for (int dt = 0; dt < 16; ++dt) {
    const int dir = dt >> 3, t = dt & 7;
    const int len = dir ? len_b : len_f;
    const int widx = dir ? (6 + len - t) : (8 - len + t);  // always in [0,14]
    const float* src = win + ((size_t)s * 15 + widx) * 512 + tid * 2;
    u16* dst = xg + ((size_t)dt * 8192 + slot) * 512 + tid * 2;
    float2 v = *(const float2*)src;
    *(unsigned*)dst = (unsigned)f2bf(v.x) | ((unsigned)f2bf(v.y) << 16);
  }
}

// ---------------------------------------------------------------------------
// gru_fused v3 -- ROUND-11 FIX. Eleven-round diagnosis: every spilling
// variant (r0-3, r9, r10: WRITE 3-7GB) HOLDS packed h_new in registers
// across later passes' fully-unrolled K-loops; the only no-spill family
// (gru_rec) double-buffers h and holds NOTHING. So: fuse with the no-hold
// structure. LDS = h double-buffer ONLY (133KB fits); the x-half MFMA
// A-fragments are read DIRECTLY FROM GLOBAL xg (bf16, 16B/lane, 64B
// segments; the 64KB/block/step slice is L2-hot) -- no x_s staging, no
// BAR_A, zero held values, ONE barrier per step.
// 256 blocks x 1024 threads; wave = rh(2) x wc(8); 4 passes x 16 cols x
// 32 rows; acc = 4 gates x 2 mt = 32 AGPR; arch ~60 regs -> no spill.
// dir = blockIdx&1 -> each XCD caches ONE direction's 3MB Wp.
// ---------------------------------------------------------------------------
#define LROW 520  // padded LDS row stride (bf16)

__global__ __launch_bounds__(1024)
__attribute__((amdgpu_waves_per_eu(4, 4))) void gru_fused(
    const int* __restrict__ wlen, const int* __restrict__ order,
    const u16* __restrict__ Wp_f, const u16* __restrict__ Wp_b,
    const float* __restrict__ bih_f, const float* __restrict__ bhh_f,
    const float* __restrict__ bih_b, const float* __restrict__ bhh_b,
    const u16* __restrict__ xg, u16* __restrict__ hcat) {
  extern __shared__ char smem[];
  u16* hb0 = (u16*)smem;       // [64][LROW]
  u16* hb1 = hb0 + 64 * LROW;  // [64][LROW]
  int* len_s = (int*)(hb1 + 64 * LROW);
  int* bmax_s = len_s + 64;

  const int dir = blockIdx.x & 1;
  const int grp = blockIdx.x >> 1;
  const int s0 = grp * 64;
  const u16* W = dir ? Wp_b : Wp_f;
  const float* bih = dir ? bih_b : bih_f;
  const float* bhh = dir ? bhh_b : bhh_f;

  const int tid = threadIdx.x;
  const int wave = tid >> 6;  // 0..15
  const int rh = wave & 1;    // row half (0: rows 0-31, 1: rows 32-63)
  const int wc = wave >> 1;   // col group 0..7
  const int lane = tid & 63;
  const int ln = lane & 15;
  const int ks = lane >> 4;  // 0..3

  // ---- init: zero hb0, lengths (sorted) + block max ----
  if (tid == 0) *bmax_s = 0;
  for (int i = tid; i < 64 * LROW / 8; i += 1024) ((u16x8*)hb0)[i] = (u16x8)0;
  __syncthreads();
  if (tid < 64) {
    int wl = wlen[order[s0 + tid]];
    int len = dir ? (wl / 2 + 1) : ((wl - 1) / 2 + 1);
    len_s[tid] = len;
    atomicMax(bmax_s, len);
  }
  __syncthreads();
  const int bmax = *bmax_s;

  // ---- biases: one 16-col chunk per (pass, wave-col-group) ----
  float b_r[4], b_z[4], b_xn[4], b_hn[4];
#pragma unroll
  for (int p = 0; p < 4; ++p) {
    int d = (p * 8 + wc) * 16 + ln;
    b_r[p] = bih[d] + bhh[d];
    b_z[p] = bih[512 + d] + bhh[512 + d];
    b_xn[p] = bih[1024 + d];
    b_hn[p] = bhh[1024 + d];
  }

  for (int t = 0; t < bmax; ++t) {
    u16* h_cur = (t & 1) ? hb1 : hb0;
    u16* h_nxt = (t & 1) ? hb0 : hb1;
    // this block's x rows for step t (bf16, sorted slots, row = slot - s0)
    const u16* xgs = xg + ((size_t)(dir * 8 + t) * 8192 + s0) * 512;

#pragma unroll
    for (int p = 0; p < 4; ++p) {
      const int q = p * 8 + wc;  // gate-col chunk 0..31
      const int dcol = q * 16 + ln;
      const u16* wq = W + (size_t)q * 49152 + lane * 8;  // fragment-ordered

      f32x4 accr[2], accz[2], acchn[2], accxn[2];
#pragma unroll
      for (int mt = 0; mt < 2; ++mt)
#pragma unroll
        for (int j = 0; j < 4; ++j) {
          accr[mt][j] = 0.f; accz[mt][j] = 0.f;
          acchn[mt][j] = 0.f; accxn[mt][j] = 0.f;
        }

      // K-loop, h half (kk 0..15): A from LDS h_cur; accumulate r, z, hn
#pragma unroll
      for (int kk = 0; kk < 16; ++kk) {
        const int krel = kk * 32 + ks * 8;
        bf16x8 a[2];
#pragma unroll
        for (int mt = 0; mt < 2; ++mt)
          a[mt] = *(const bf16x8*)(h_cur + (rh * 32 + mt * 16 + ln) * LROW + krel);
        const u16* wk = wq + kk * 1536;
        bf16x8 br = *(const bf16x8*)(wk);
        bf16x8 bz = *(const bf16x8*)(wk + 512);
        bf16x8 bn = *(const bf16x8*)(wk + 1024);
#pragma unroll
        for (int mt = 0; mt < 2; ++mt) {
          accr[mt] = MFMA(a[mt], br, accr[mt]);
          accz[mt] = MFMA(a[mt], bz, accz[mt]);
          acchn[mt] = MFMA(a[mt], bn, acchn[mt]);
        }
      }
      // K-loop, x half (kk 16..31): A DIRECT FROM GLOBAL xg (L2-hot 64KB
      // slice, 16B/lane aligned); accumulate r, z, xn
#pragma unroll
      for (int kk = 0; kk < 16; ++kk) {
        const int krel = kk * 32 + ks * 8;
        bf16x8 a[2];
#pragma unroll
        for (int mt = 0; mt < 2; ++mt)
          a[mt] = *(const bf16x8*)(xgs + (size_t)(rh * 32 + mt * 16 + ln) * 512 + krel);
        const u16* wk = wq + (16 + kk) * 1536;
        bf16x8 br = *(const bf16x8*)(wk);
        bf16x8 bz = *(const bf16x8*)(wk + 512);
        bf16x8 bn = *(const bf16x8*)(wk + 1024);
#pragma unroll
        for (int mt = 0; mt < 2; ++mt) {
          accr[mt] = MFMA(a[mt], br, accr[mt]);
          accz[mt] = MFMA(a[mt], bz, accz[mt]);
          accxn[mt] = MFMA(a[mt], bn, accxn[mt]);
        }
      }

      // epilogue: write h_new straight to the OTHER buffer (no holding;
      // each (row,col) owned by exactly one wave: rows rh*32.., cols q*16..)
#pragma unroll
      for (int mt = 0; mt < 2; ++mt)
#pragma unroll
        for (int j = 0; j < 4; ++j) {
          const int row = rh * 32 + mt * 16 + ks * 4 + j;
          float rr = sigm(accr[mt][j] + b_r[p]);
          float zz = sigm(accz[mt][j] + b_z[p]);
          float nn = tanh_(accxn[mt][j] + b_xn[p] +
                           rr * (acchn[mt][j] + b_hn[p]));
          float hold = bf2f(h_cur[row * LROW + dcol]);
          float hnew = (t < len_s[row]) ? ((1.f - zz) * nn + zz * hold) : hold;
          h_nxt[row * LROW + dcol] = f2bf(hnew);
        }
    }  // passes
    __syncthreads();  // h_nxt complete before it becomes h_cur
  }    // t

  // ---- write final h to hcat[slot][dir*512 + k] ----
  const u16* hf = (bmax & 1) ? hb1 : hb0;
  const int xrow = tid >> 4;  // 0..63
  const int xseg = tid & 15;  // 0..15
#pragma unroll
  for (int i = 0; i < 4; ++i) {
    int off = (i * 16 + xseg) * 8;
    u16x8 v = *(const u16x8*)(hf + xrow * LROW + off);
    __builtin_nontemporal_store(
        v, (u16x8*)(hcat + (size_t)(s0 + xrow) * 1024 + dir * 512 + off));
  }
}

// ---------------------------------------------------------------------------
// FALLBACK path (ws too small): round-2 fused kernel (no sort needed).
// ---------------------------------------------------------------------------
__global__ __launch_bounds__(256) void build_wcat(const float* __restrict__ Whh,
                                                  const float* __restrict__ Wih,
                                                  u16* __restrict__ Wcat) {
  int i = blockIdx.x * 256 + threadIdx.x;
  if (i >= 1536 * 1024 / 8) return;
  int e = i * 8;
  int g = e >> 10, k = e & 1023;
  const float* src = (k < 512) ? (Whh + g * 512 + k) : (Wih + g * 512 + (k - 512));
  u16x8 o;
#pragma unroll
  for (int j = 0; j < 8; ++j) o[j] = f2bf(src[j]);
  *(u16x8*)(Wcat + e) = o;
}

__global__ __launch_bounds__(512)
__attribute__((amdgpu_waves_per_eu(2, 2))) void gru_persistent(
    const float* __restrict__ win, const int* __restrict__ wlen,
    const u16* __restrict__ Wcat_f, const u16* __restrict__ Wcat_b,
    const float* __restrict__ bih_f, const float* __restrict__ bhh_f,
    const float* __restrict__ bih_b, const float* __restrict__ bhh_b,
    u16* __restrict__ hcat) {
  extern __shared__ char smem[];
  u16* h_s = (u16*)smem;
  u16* x_s = (u16*)(smem + 64 * LROW * 2);
  int* len_s = (int*)(smem + 2 * 64 * LROW * 2);
  int* bmax_s = len_s + 64;

  const int dir = blockIdx.x & 1;
  const int grp = blockIdx.x >> 1;
  const int s0 = grp * 64;
  const u16* W = dir ? Wcat_b : Wcat_f;
  const float* bih = dir ? bih_b : bih_f;
  const float* bhh = dir ? bhh_b : bhh_f;

  const int tid = threadIdx.x;
  const int wave = tid >> 6;
  const int lane = tid & 63;
  const int ln = lane & 15;
  const int ks = lane >> 4;

  if (tid == 0) *bmax_s = 0;
  for (int i = tid; i < 64 * LROW / 8; i += 512) ((u16x8*)h_s)[i] = (u16x8)0;
  __syncthreads();
  if (tid < 64) {
    int wl = wlen[s0 + tid];
    int len = dir ? (wl / 2 + 1) : ((wl - 1) / 2 + 1);
    len_s[tid] = len;
    atomicMax(bmax_s, len);
  }
  __syncthreads();
  const int bmax = *bmax_s;

  float b_r[4], b_z[4], b_xn[4], b_hn[4];
#pragma unroll
  for (int p = 0; p < 4; ++p) {
    int d = (p * 8 + wave) * 16 + ln;
    b_r[p] = bih[d] + bhh[d];
    b_z[p] = bih[512 + d] + bhh[512 + d];
    b_xn[p] = bih[1024 + d];
    b_hn[p] = bhh[1024 + d];
  }

  const int xrow = tid >> 3;
  const int xcol = tid & 7;
  const int mylen = len_s[xrow];
  const long xbase = (long)(s0 + xrow) * 15 + (dir ? (6 + mylen) : (8 - mylen));

  for (int t = 0; t < bmax; ++t) {
    {
      long rowidx = dir ? (xbase - t) : (xbase + t);
      const float* src = win + rowidx * 512;
      u16* dst = x_s + xrow * LROW;
#pragma unroll
      for (int i = 0; i < 8; ++i) {
        int off = xcol * 8 + i * 64;
        f32x4 v0 = *(const f32x4*)(src + off);
        f32x4 v1 = *(const f32x4*)(src + off + 4);
        u16x8 o;
        o[0] = f2bf(v0[0]); o[1] = f2bf(v0[1]); o[2] = f2bf(v0[2]); o[3] = f2bf(v0[3]);
        o[4] = f2bf(v1[0]); o[5] = f2bf(v1[1]); o[6] = f2bf(v1[2]); o[7] = f2bf(v1[3]);
        *(u16x8*)(dst + off) = o;
      }
    }
    __syncthreads();

    unsigned holdp[3][4][2];

#pragma unroll
    for (int p = 0; p < 4; ++p) {
      const int dcol = (p * 8 + wave) * 16 + ln;
      const u16* wrow = W + (size_t)dcol * 1024;

      f32x4 accr[4], accz[4], acchn[4], accxn[4];
#pragma unroll
      for (int mt = 0; mt < 4; ++mt)
#pragma unroll
        for (int j = 0; j < 4; ++j) {
          accr[mt][j] = 0.f; accz[mt][j] = 0.f;
          acchn[mt][j] = 0.f; accxn[mt][j] = 0.f;
        }

#pragma unroll
      for (int kk = 0; kk < 16; ++kk) {
        const int krel = kk * 32 + ks * 8;
        bf16x8 a[4];
#pragma unroll
        for (int mt = 0; mt < 4; ++mt)
          a[mt] = *(const bf16x8*)(h_s + (mt * 16 + ln) * LROW + krel);
        bf16x8 br = *(const bf16x8*)(wrow + krel);
        bf16x8 bz = *(const bf16x8*)(wrow + 512 * 1024 + krel);
        bf16x8 bn = *(const bf16x8*)(wrow + 1024 * 1024 + krel);
#pragma unroll
        for (int mt = 0; mt < 4; ++mt) {
          accr[mt] = MFMA(a[mt], br, accr[mt]);
          accz[mt] = MFMA(a[mt], bz, accz[mt]);
          acchn[mt] = MFMA(a[mt], bn, acchn[mt]);
        }
      }
#pragma unroll
      for (int kk = 0; kk < 16; ++kk) {
        const int krel = kk * 32 + ks * 8;
        bf16x8 a[4];
#pragma unroll
        for (int mt = 0; mt < 4; ++mt)
          a[mt] = *(const bf16x8*)(x_s + (mt * 16 + ln) * LROW + krel);
        bf16x8 br = *(const bf16x8*)(wrow + 512 + krel);
        bf16x8 bz = *(const bf16x8*)(wrow + 512 * 1024 + 512 + krel);
        bf16x8 bn = *(const bf16x8*)(wrow + 1024 * 1024 + 512 + krel);
#pragma unroll
        for (int mt = 0; mt < 4; ++mt) {
          accr[mt] = MFMA(a[mt], br, accr[mt]);
          accz[mt] = MFMA(a[mt], bz, accz[mt]);
          accxn[mt] = MFMA(a[mt], bn, accxn[mt]);
        }
      }

      if (p < 3) {
#pragma unroll
        for (int mt = 0; mt < 4; ++mt)
#pragma unroll
          for (int jp = 0; jp < 2; ++jp) {
            unsigned pk = 0;
#pragma unroll
            for (int jh = 0; jh < 2; ++jh) {
              const int j = jp * 2 + jh;
              const int row = mt * 16 + ks * 4 + j;
              float rr = sigm(accr[mt][j] + b_r[p]);
              float zz = sigm(accz[mt][j] + b_z[p]);
              float nn = tanh_(accxn[mt][j] + b_xn[p] +
                               rr * (acchn[mt][j] + b_hn[p]));
              float hold = bf2f(h_s[row * LROW + dcol]);
              float hnew = (t < len_s[row]) ? ((1.f - zz) * nn + zz * hold) : hold;
              pk |= ((unsigned)f2bf(hnew)) << (16 * jh);
            }
            holdp[p][mt][jp] = pk;
          }
      } else {
        __syncthreads();
#pragma unroll
        for (int pp = 0; pp < 3; ++pp) {
          const int dd = (pp * 8 + wave) * 16 + ln;
#pragma unroll
          for (int mt = 0; mt < 4; ++mt)
#pragma unroll
            for (int jp = 0; jp < 2; ++jp) {
              unsigned pk = holdp[pp][mt][jp];
              const int row = mt * 16 + ks * 4 + jp * 2;
              h_s[row * LROW + dd] = (u16)pk;
              h_s[(row + 1) * LROW + dd] = (u16)(pk >> 16);
            }
        }
#pragma unroll
        for (int mt = 0; mt < 4; ++mt)
#pragma unroll
          for (int j = 0; j < 4; ++j) {
            const int row = mt * 16 + ks * 4 + j;
            float rr = sigm(accr[mt][j] + b_r[3]);
            float zz = sigm(accz[mt][j] + b_z[3]);
            float nn = tanh_(accxn[mt][j] + b_xn[3] +
                             rr * (acchn[mt][j] + b_hn[3]));
            float hold = bf2f(h_s[row * LROW + dcol]);
            float hnew = (t < len_s[row]) ? ((1.f - zz) * nn + zz * hold) : hold;
            h_s[row * LROW + dcol] = f2bf(hnew);
          }
      }
    }
  }

  __syncthreads();
#pragma unroll
  for (int i = 0; i < 8; ++i) {
    int off = xcol * 8 + i * 64;
    u16x8 v = *(const u16x8*)(h_s + xrow * LROW + off);
    __builtin_nontemporal_store(
        v, (u16x8*)(hcat + (size_t)(s0 + xrow) * 1024 + dir * 512 + off));
  }
}

// ---------------------------------------------------------------------------
// MLP GEMM: out[M,N] = act(A[M,K] @ Bw[N,K]^T + bias)
// perm != nullptr: store row goes to perm[row] (undoes the length sort).
// ---------------------------------------------------------------------------
__global__ __launch_bounds__(256) void mlp_gemm(const u16* __restrict__ A,
                                                const u16* __restrict__ Bw,
                                                const float* __restrict__ bias,
                                                const int* __restrict__ perm,
                                                void* __restrict__ out, int M,
                                                int N, int K, int mode) {
  __shared__ u16 As[128 * 64], Bs[128 * 64];
  const int tid = threadIdx.x;
  const int wave = tid >> 6, lane = tid & 63;
  const int ln = lane & 15, ks = lane >> 4;
  const int wm = wave & 1, wn = wave >> 1;
  const int m0 = blockIdx.x * 128, n0 = blockIdx.y * 128;
  f32x4 acc[4][4];
#pragma unroll
  for (int mt = 0; mt < 4; ++mt)
#pragma unroll
    for (int nt = 0; nt < 4; ++nt)
#pragma unroll
      for (int j = 0; j < 4; ++j) acc[mt][nt][j] = 0.f;

  const int r = tid >> 1, hh = tid & 1;
  for (int k0 = 0; k0 < K; k0 += 64) {
    const i32x4* sa = (const i32x4*)(A + (size_t)(m0 + r) * K + k0 + hh * 32);
    const i32x4* sb = (const i32x4*)(Bw + (size_t)(n0 + r) * K + k0 + hh * 32);
    i32x4* da = (i32x4*)(As + r * 64 + hh * 32);
    i32x4* db = (i32x4*)(Bs + r * 64 + hh * 32);
#pragma unroll
    for (int i = 0; i < 4; ++i) da[i] = sa[i];
#pragma unroll
    for (int i = 0; i < 4; ++i) db[i] = sb[i];
    __syncthreads();
#pragma unroll
    for (int kk = 0; kk < 2; ++kk) {
      bf16x8 af[4], bfm[4];
#pragma unroll
      for (int mt = 0; mt < 4; ++mt)
        af[mt] = *(const bf16x8*)(As + (wm * 64 + mt * 16 + ln) * 64 + kk * 32 + ks * 8);
#pragma unroll
      for (int nt = 0; nt < 4; ++nt)
        bfm[nt] = *(const bf16x8*)(Bs + (wn * 64 + nt * 16 + ln) * 64 + kk * 32 + ks * 8);
#pragma unroll
      for (int mt = 0; mt < 4; ++mt)
#pragma unroll
        for (int nt = 0; nt < 4; ++nt) acc[mt][nt] = MFMA(af[mt], bfm[nt], acc[mt][nt]);
    }
    __syncthreads();
  }

#pragma unroll
  for (int nt = 0; nt < 4; ++nt) {
    int col = n0 + wn * 64 + nt * 16 + ln;
    float bv = bias[col];
#pragma unroll
    for (int mt = 0; mt < 4; ++mt)
#pragma unroll
      for (int j = 0; j < 4; ++j) {
        int row = m0 + wm * 64 + mt * 16 + ks * 4 + j;
        float v = acc[mt][nt][j] + bv;
        int orow = perm ? perm[row] : row;
        if (mode) {
          v = fmaxf(v, 0.f);
          ((u16*)out)[(size_t)orow * N + col] = f2bf(v);
        } else {
          ((float*)out)[(size_t)orow * N + col] = v;
        }
      }
  }
}

// ---------------------------------------------------------------------------
extern "C" void kernel_launch(void* const* d_in, const int* in_sizes, int n_in,
                              void* d_out, int out_size, void* d_ws, size_t ws_size,
                              hipStream_t stream) {
  (void)in_sizes; (void)n_in; (void)out_size;
  const float* win = (const float*)d_in[0];
  const int* wlen = (const int*)d_in[1];
  const float* Wih_f = (const float*)d_in[2];
  const float* Whh_f = (const float*)d_in[3];
  const float* bih_f = (const float*)d_in[4];
  const float* bhh_f = (const float*)d_in[5];
  const float* Wih_b = (const float*)d_in[6];
  const float* Whh_b = (const float*)d_in[7];
  const float* bih_b = (const float*)d_in[8];
  const float* bhh_b = (const float*)d_in[9];
  const float* W1 = (const float*)d_in[10];
  const float* b1 = (const float*)d_in[11];
  const float* W2 = (const float*)d_in[12];
  const float* b2 = (const float*)d_in[13];

  // main path: Wp 2x3MB + W1b + W2b + hcat + hidden + order/rank + xg 128MB
  const size_t NEED = 2ull * 3145728 + 1048576 + 524288 + 16777216 + 8388608 +
                      65536 + 134217728ull;  // = 167,313,408

  if (ws_size >= NEED) {
    char* ws = (char*)d_ws;
    u16* Wp_f = (u16*)ws;   ws += 3145728;
    u16* Wp_b = (u16*)ws;   ws += 3145728;
    u16* W1b = (u16*)ws;    ws += 1048576;
    u16* W2b = (u16*)ws;    ws += 524288;
    u16* hcat = (u16*)ws;   ws += 16777216;
    u16* hidden = (u16*)ws; ws += 8388608;
    int* order = (int*)ws;  ws += 32768;
    int* rank = (int*)ws;   ws += 32768;
    u16* xg = (u16*)ws;     ws += 134217728;

    sort_len<<<1, 1024, 0, stream>>>(wlen, order, rank);
    wrepack_cat<<<768, 256, 0, stream>>>(Whh_f, Wih_f, Wp_f);
    wrepack_cat<<<768, 256, 0, stream>>>(Whh_b, Wih_b, Wp_b);
    cvt_bf16<<<256, 256, 0, stream>>>(W1, W1b, 65536);
    cvt_bf16<<<128, 256, 0, stream>>>(W2, W2b, 32768);

    xgather<<<8192, 256, 0, stream>>>(win, wlen, rank, xg);

    const int SMEM = 2 * 64 * LROW * 2 + 64 * 4 + 16;  // h dbuf + lens + bmax
    (void)hipFuncSetAttribute((const void*)gru_fused,
                              hipFuncAttributeMaxDynamicSharedMemorySize, SMEM);
    gru_fused<<<256, 1024, SMEM, stream>>>(wlen, order, Wp_f, Wp_b, bih_f,
                                           bhh_f, bih_b, bhh_b, xg, hcat);

    mlp_gemm<<<dim3(64, 4), 256, 0, stream>>>(hcat, W1b, b1, nullptr, hidden,
                                              8192, 512, 1024, 1);
    mlp_gemm<<<dim3(64, 4), 256, 0, stream>>>(hidden, W2b, b2, order, d_out,
                                              8192, 512, 512, 0);
  } else {
    char* ws = (char*)d_ws;
    u16* Wcat_f = (u16*)ws;  ws += 3145728;
    u16* Wcat_b = (u16*)ws;  ws += 3145728;
    u16* W1b = (u16*)ws;     ws += 1048576;
    u16* W2b = (u16*)ws;     ws += 524288;
    u16* hcat = (u16*)ws;    ws += 16777216;
    u16* hidden = (u16*)ws;  ws += 8388608;

    build_wcat<<<768, 256, 0, stream>>>(Whh_f, Wih_f, Wcat_f);
    build_wcat<<<768, 256, 0, stream>>>(Whh_b, Wih_b, Wcat_b);
    cvt_bf16<<<256, 256, 0, stream>>>(W1, W1b, 65536);
    cvt_bf16<<<128, 256, 0, stream>>>(W2, W2b, 32768);

    const int SMEM = 2 * 64 * LROW * 2 + 64 * 4 + 16;
    (void)hipFuncSetAttribute((const void*)gru_persistent,
                              hipFuncAttributeMaxDynamicSharedMemorySize, SMEM);
    gru_persistent<<<256, 512, SMEM, stream>>>(win, wlen, Wcat_f, Wcat_b, bih_f,
                                               bhh_f, bih_b, bhh_b, hcat);

    mlp_gemm<<<dim3(64, 4), 256, 0, stream>>>(hcat, W1b, b1, nullptr, hidden,
                                              8192, 512, 1024, 1);
    mlp_gemm<<<dim3(64, 4), 256, 0, stream>>>(hidden, W2b, b2, nullptr, d_out,
                                              8192, 512, 512, 0);
  }
}

// Round 13
// 2040.385 us; speedup vs baseline: 2.9653x; 1.7417x over previous
//
#include <hip/hip_runtime.h>

typedef unsigned short u16;
typedef __attribute__((ext_vector_type(4))) float f32x4;
typedef __attribute__((ext_vector_type(8))) __bf16 bf16x8;
typedef __attribute__((ext_vector_type(8))) u16 u16x8;
typedef __attribute__((ext_vector_type(4))) u16 u16x4;
typedef __attribute__((ext_vector_type(4))) int i32x4;

#define MFMA(a, b, c) __builtin_amdgcn_mfma_f32_16x16x32_bf16(a, b, c, 0, 0, 0)

__device__ __forceinline__ u16 f2bf(float f) {
  union { float f; unsigned u; } v; v.f = f;
  unsigned r = v.u + 0x7FFFu + ((v.u >> 16) & 1u);
  return (u16)(r >> 16);
}
__device__ __forceinline__ float bf2f(u16 b) {
  union { unsigned u; float f; } v; v.u = ((unsigned)b) << 16; return v.f;
}
__device__ __forceinline__ float sigm(float x) { return 1.f / (1.f + __expf(-x)); }
__device__ __forceinline__ float tanh_(float x) {
  float e = __expf(-2.f * fabsf(x));
  float r = (1.f - e) / (1.f + e);
  return x < 0.f ? -r : r;
}

// xp layout: plane = (dir*8 + t)*96 + g  (g = col>>4). Within plane:
// offset = (slot>>2)*64 + (col&15)*4 + (slot&3).  GSTRIDE elems per plane.
// slot = position in length-sorted order.
#define GSTRIDE 131072

// ---------------------------------------------------------------------------
__global__ __launch_bounds__(256) void cvt_bf16(const float* __restrict__ src,
                                                u16* __restrict__ dst, int n8) {
  int i = blockIdx.x * 256 + threadIdx.x;
  if (i >= n8) return;
  int e = i * 8;
  u16x8 o;
#pragma unroll
  for (int j = 0; j < 8; ++j) o[j] = f2bf(src[e + j]);
  *(u16x8*)(dst + e) = o;
}

// ---------------------------------------------------------------------------
// wrepack: Whh (f32 1536x512) -> fragment-ordered bf16 Wp so that one wave
// weight load in gru_rec is 1KB CONTIGUOUS.
// ---------------------------------------------------------------------------
__global__ __launch_bounds__(256) void wrepack(const float* __restrict__ Whh,
                                               u16* __restrict__ Wp) {
  int i = blockIdx.x * 256 + threadIdx.x;  // one u16x8 per thread
  if (i >= 98304) return;
  int q = i / 3072;
  int r1 = i % 3072;
  int kk = r1 / 192;
  int r2 = r1 % 192;
  int g = r2 / 64;
  int r3 = r2 % 64;
  int ks = r3 >> 4, ln = r3 & 15;
  const float* src =
      Whh + (size_t)(g * 512 + q * 16 + ln) * 512 + kk * 32 + ks * 8;
  u16x8 o;
#pragma unroll
  for (int j = 0; j < 8; ++j) o[j] = f2bf(src[j]);
  *(u16x8*)(Wp + (size_t)i * 8) = o;
}

// ---------------------------------------------------------------------------
// sort_len: counting-sort sample ids by window_len (1..15); order[slot]=sample,
// rank[sample]=slot.
// ---------------------------------------------------------------------------
__global__ __launch_bounds__(1024) void sort_len(const int* __restrict__ wlen,
                                                 int* __restrict__ order,
                                                 int* __restrict__ rank) {
  __shared__ int cnt[16];
  __shared__ int off[16];
  const int tid = threadIdx.x;
  if (tid < 16) cnt[tid] = 0;
  __syncthreads();
  for (int i = tid; i < 8192; i += 1024) atomicAdd(&cnt[wlen[i] - 1], 1);
  __syncthreads();
  if (tid == 0) {
    int run = 0;
#pragma unroll
    for (int b = 0; b < 15; ++b) { off[b] = run; run += cnt[b]; }
  }
  __syncthreads();
  for (int i = tid; i < 8192; i += 1024) {
    int pos = atomicAdd(&off[wlen[i] - 1], 1);
    order[pos] = i;
    rank[i] = pos;
  }
}

// ---------------------------------------------------------------------------
// xp_gemm (round-12): the measured-best R6 design (128-slot t-major tile,
// dead-block early-exit, dense slot stores) with ONE change: 512 threads
// (8 waves -> 2 waves/SIMD, was 1) for 2x latency hiding at the SAME tile
// size (smaller tiles measured worse: B-stream amplification, R8=994us).
// Each wave: 12 n-chunks in 3 groups of 4, full M=128.
// Biases bih (+bhh for r,z) folded into xp.
// ---------------------------------------------------------------------------
#define LROWA 520  // LDS A row stride (bf16 elems)

__global__ __launch_bounds__(512)
__attribute__((amdgpu_waves_per_eu(2, 2))) void xp_gemm(
    const float* __restrict__ win, const int* __restrict__ wlen,
    const int* __restrict__ order, const u16* __restrict__ Wihb_f,
    const u16* __restrict__ Wihb_b, const float* __restrict__ bih_f,
    const float* __restrict__ bih_b, const float* __restrict__ bhh_f,
    const float* __restrict__ bhh_b, u16* __restrict__ xp) {
  extern __shared__ char smem[];
  u16* As = (u16*)smem;  // [128][LROWA]

  const int dir = blockIdx.z;
  const int t = blockIdx.y;
  const int sbase = blockIdx.x * 128;

  // dead-block check (uniform): sorted ascending -> last slot has max len
  {
    int wl_last = wlen[order[sbase + 127]];
    int len_last = dir ? (wl_last / 2 + 1) : ((wl_last - 1) / 2 + 1);
    if (len_last <= t) return;
  }

  const u16* Wb = dir ? Wihb_b : Wihb_f;
  const float* bih = dir ? bih_b : bih_f;
  const float* bhh = dir ? bhh_b : bhh_f;

  const int tid = threadIdx.x;

  // ---- stage A: 128 sorted-slot rows at this t, f32 -> bf16 ----
  {
    const int r = tid >> 2, qq = tid & 3;  // 4 threads/row, 128 elems each
    const int sample = order[sbase + r];
    const int wl = wlen[sample];
    const int len = dir ? (wl / 2 + 1) : ((wl - 1) / 2 + 1);
    const int widx = dir ? (6 + len - t) : (8 - len + t);  // always in [0,14]
    const float* src = win + ((size_t)sample * 15 + widx) * 512 + qq * 128;
    u16* dst = As + r * LROWA + qq * 128;
#pragma unroll
    for (int i = 0; i < 16; ++i) {
      f32x4 v0 = *(const f32x4*)(src + i * 8);
      f32x4 v1 = *(const f32x4*)(src + i * 8 + 4);
      u16x8 o;
      o[0] = f2bf(v0[0]); o[1] = f2bf(v0[1]); o[2] = f2bf(v0[2]); o[3] = f2bf(v0[3]);
      o[4] = f2bf(v1[0]); o[5] = f2bf(v1[1]); o[6] = f2bf(v1[2]); o[7] = f2bf(v1[3]);
      *(u16x8*)(dst + i * 8) = o;
    }
  }
  __syncthreads();

  const int wave = tid >> 6;  // 0..7
  const int lane = tid & 63;
  const int ln = lane & 15;
  const int ks = lane >> 4;

#pragma unroll 1
  for (int g = 0; g < 3; ++g) {
    const int c0 = wave * 12 + g * 4;  // 4 n-chunks per group

    f32x4 acc[8][4];
#pragma unroll
    for (int mt = 0; mt < 8; ++mt)
#pragma unroll
      for (int u = 0; u < 4; ++u)
#pragma unroll
        for (int j = 0; j < 4; ++j) acc[mt][u][j] = 0.f;

#pragma unroll
    for (int kk = 0; kk < 16; ++kk) {
      const int krel = kk * 32 + ks * 8;
      bf16x8 a[8];
#pragma unroll
      for (int mt = 0; mt < 8; ++mt)
        a[mt] = *(const bf16x8*)(As + (mt * 16 + ln) * LROWA + krel);
      bf16x8 b[4];
#pragma unroll
      for (int u = 0; u < 4; ++u)
        b[u] = *(const bf16x8*)(Wb + (size_t)((c0 + u) * 16 + ln) * 512 + krel);
#pragma unroll
      for (int mt = 0; mt < 8; ++mt)
#pragma unroll
        for (int u = 0; u < 4; ++u) acc[mt][u] = MFMA(a[mt], b[u], acc[mt][u]);
    }

    // epilogue: fold biases, store to slot-indexed xp layout (contiguous
    // slots within block -> dense lines, no RMW)
#pragma unroll
    for (int u = 0; u < 4; ++u) {
      const int col = (c0 + u) * 16 + ln;
      const float bv = bih[col] + (col < 1024 ? bhh[col] : 0.f);
#pragma unroll
      for (int mt = 0; mt < 8; ++mt)
#pragma unroll
        for (int j = 0; j < 4; ++j) {
          const int slot = sbase + mt * 16 + ks * 4 + j;
          const size_t idx = ((size_t)(dir * 8 + t) * 96 + (c0 + u)) * GSTRIDE +
                             (size_t)(slot >> 2) * 64 + ln * 4 + (slot & 3);
          xp[idx] = f2bf(acc[mt][u][j] + bv);
        }
    }
  }
}

// ---------------------------------------------------------------------------
// gru_rec (round-8 measured 881us, refchecked): sorted slots, fragment-
// ordered Wp (1KB contiguous wave loads), h double-buffered in LDS, ONE
// barrier per step, xp prefetched pre-K-loop as vectorized u16x4 loads.
// ---------------------------------------------------------------------------
#define LROW 520  // padded LDS row stride (bf16) to break bank conflicts

__global__ __launch_bounds__(1024)
__attribute__((amdgpu_waves_per_eu(4, 4))) void gru_rec(
    const int* __restrict__ wlen, const int* __restrict__ order,
    const u16* __restrict__ Wp_f, const u16* __restrict__ Wp_b,
    const float* __restrict__ bhh_f, const float* __restrict__ bhh_b,
    const u16* __restrict__ xp, u16* __restrict__ hcat) {
  extern __shared__ char smem[];
  u16* hb0 = (u16*)smem;       // [64][LROW]
  u16* hb1 = hb0 + 64 * LROW;  // [64][LROW]
  int* len_s = (int*)(hb1 + 64 * LROW);
  int* bmax_s = len_s + 64;

  const int dir = blockIdx.x & 1;
  const int grp = blockIdx.x >> 1;
  const int s0 = grp * 64;
  const u16* W = dir ? Wp_b : Wp_f;
  const float* bhh = dir ? bhh_b : bhh_f;

  const int tid = threadIdx.x;
  const int wave = tid >> 6;  // 0..15
  const int lane = tid & 63;
  const int ln = lane & 15;
  const int ks = lane >> 4;  // 0..3

  if (tid == 0) *bmax_s = 0;
  for (int i = tid; i < 64 * LROW / 8; i += 1024) ((u16x8*)hb0)[i] = (u16x8)0;
  __syncthreads();
  if (tid < 64) {
    int wl = wlen[order[s0 + tid]];
    int len = dir ? (wl / 2 + 1) : ((wl - 1) / 2 + 1);
    len_s[tid] = len;
    atomicMax(bmax_s, len);
  }
  __syncthreads();
  const int bmax = *bmax_s;

  float b_hn[2];
#pragma unroll
  for (int p = 0; p < 2; ++p) b_hn[p] = bhh[1024 + (p * 16 + wave) * 16 + ln];

  for (int t = 0; t < bmax; ++t) {
    u16* h_cur = (t & 1) ? hb1 : hb0;
    u16* h_nxt = (t & 1) ? hb0 : hb1;
    const u16* xpt = xp + (size_t)(dir * 8 + t) * 96 * GSTRIDE;

#pragma unroll
    for (int p = 0; p < 2; ++p) {
      const int q = p * 16 + wave;  // gate-col chunk 0..31
      const int dcol = q * 16 + ln;
      const u16* wq = W + (size_t)q * 24576 + lane * 8;  // fragment-ordered

      u16x4 xr4[4], xz4[4], xn4[4];
#pragma unroll
      for (int mt = 0; mt < 4; ++mt) {
        const size_t off = (size_t)((s0 >> 2) + mt * 4 + ks) * 64 + ln * 4;
        xr4[mt] = *(const u16x4*)(xpt + (size_t)q * GSTRIDE + off);
        xz4[mt] = *(const u16x4*)(xpt + (size_t)(32 + q) * GSTRIDE + off);
        xn4[mt] = *(const u16x4*)(xpt + (size_t)(64 + q) * GSTRIDE + off);
      }

      f32x4 accr[4], accz[4], acchn[4];
#pragma unroll
      for (int mt = 0; mt < 4; ++mt)
#pragma unroll
        for (int j = 0; j < 4; ++j) {
          accr[mt][j] = 0.f; accz[mt][j] = 0.f; acchn[mt][j] = 0.f;
        }

#pragma unroll
      for (int kk = 0; kk < 16; ++kk) {
        const int krel = kk * 32 + ks * 8;
        bf16x8 a[4];
#pragma unroll
        for (int mt = 0; mt < 4; ++mt)
          a[mt] = *(const bf16x8*)(h_cur + (mt * 16 + ln) * LROW + krel);
        const u16* wk = wq + kk * 1536;
        bf16x8 br = *(const bf16x8*)(wk);  // contiguous 1KB/wave
        bf16x8 bz = *(const bf16x8*)(wk + 512);
        bf16x8 bn = *(const bf16x8*)(wk + 1024);
#pragma unroll
        for (int mt = 0; mt < 4; ++mt) {
          accr[mt] = MFMA(a[mt], br, accr[mt]);
          accz[mt] = MFMA(a[mt], bz, accz[mt]);
          acchn[mt] = MFMA(a[mt], bn, acchn[mt]);
        }
      }

#pragma unroll
      for (int mt = 0; mt < 4; ++mt)
#pragma unroll
        for (int j = 0; j < 4; ++j) {
          const int row = mt * 16 + ks * 4 + j;
          float xr = bf2f(xr4[mt][j]);
          float xz = bf2f(xz4[mt][j]);
          float xn = bf2f(xn4[mt][j]);
          float rr = sigm(accr[mt][j] + xr);
          float zz = sigm(accz[mt][j] + xz);
          float nn = tanh_(xn + rr * (acchn[mt][j] + b_hn[p]));
          float hold = bf2f(h_cur[row * LROW + dcol]);
          float hnew = (t < len_s[row]) ? ((1.f - zz) * nn + zz * hold) : hold;
          h_nxt[row * LROW + dcol] = f2bf(hnew);
        }
    }  // passes
    __syncthreads();
  }    // t

  const u16* hf = (bmax & 1) ? hb1 : hb0;
  const int xrow = tid >> 4;  // 0..63
  const int xcol = tid & 15;  // 0..15
#pragma unroll
  for (int i = 0; i < 4; ++i) {
    int off = (i * 16 + xcol) * 8;
    u16x8 v = *(const u16x8*)(hf + xrow * LROW + off);
    __builtin_nontemporal_store(
        v, (u16x8*)(hcat + (size_t)(s0 + xrow) * 1024 + dir * 512 + off));
  }
}

// ---------------------------------------------------------------------------
// FALLBACK path (ws too small): round-2 fused kernel (no sort needed).
// ---------------------------------------------------------------------------
__global__ __launch_bounds__(256) void build_wcat(const float* __restrict__ Whh,
                                                  const float* __restrict__ Wih,
                                                  u16* __restrict__ Wcat) {
  int i = blockIdx.x * 256 + threadIdx.x;
  if (i >= 1536 * 1024 / 8) return;
  int e = i * 8;
  int g = e >> 10, k = e & 1023;
  const float* src = (k < 512) ? (Whh + g * 512 + k) : (Wih + g * 512 + (k - 512));
  u16x8 o;
#pragma unroll
  for (int j = 0; j < 8; ++j) o[j] = f2bf(src[j]);
  *(u16x8*)(Wcat + e) = o;
}

__global__ __launch_bounds__(512)
__attribute__((amdgpu_waves_per_eu(2, 2))) void gru_persistent(
    const float* __restrict__ win, const int* __restrict__ wlen,
    const u16* __restrict__ Wcat_f, const u16* __restrict__ Wcat_b,
    const float* __restrict__ bih_f, const float* __restrict__ bhh_f,
    const float* __restrict__ bih_b, const float* __restrict__ bhh_b,
    u16* __restrict__ hcat) {
  extern __shared__ char smem[];
  u16* h_s = (u16*)smem;
  u16* x_s = (u16*)(smem + 64 * LROW * 2);
  int* len_s = (int*)(smem + 2 * 64 * LROW * 2);
  int* bmax_s = len_s + 64;

  const int dir = blockIdx.x & 1;
  const int grp = blockIdx.x >> 1;
  const int s0 = grp * 64;
  const u16* W = dir ? Wcat_b : Wcat_f;
  const float* bih = dir ? bih_b : bih_f;
  const float* bhh = dir ? bhh_b : bhh_f;

  const int tid = threadIdx.x;
  const int wave = tid >> 6;
  const int lane = tid & 63;
  const int ln = lane & 15;
  const int ks = lane >> 4;

  if (tid == 0) *bmax_s = 0;
  for (int i = tid; i < 64 * LROW / 8; i += 512) ((u16x8*)h_s)[i] = (u16x8)0;
  __syncthreads();
  if (tid < 64) {
    int wl = wlen[s0 + tid];
    int len = dir ? (wl / 2 + 1) : ((wl - 1) / 2 + 1);
    len_s[tid] = len;
    atomicMax(bmax_s, len);
  }
  __syncthreads();
  const int bmax = *bmax_s;

  float b_r[4], b_z[4], b_xn[4], b_hn[4];
#pragma unroll
  for (int p = 0; p < 4; ++p) {
    int d = (p * 8 + wave) * 16 + ln;
    b_r[p] = bih[d] + bhh[d];
    b_z[p] = bih[512 + d] + bhh[512 + d];
    b_xn[p] = bih[1024 + d];
    b_hn[p] = bhh[1024 + d];
  }

  const int xrow = tid >> 3;
  const int xcol = tid & 7;
  const int mylen = len_s[xrow];
  const long xbase = (long)(s0 + xrow) * 15 + (dir ? (6 + mylen) : (8 - mylen));

  for (int t = 0; t < bmax; ++t) {
    {
      long rowidx = dir ? (xbase - t) : (xbase + t);
      const float* src = win + rowidx * 512;
      u16* dst = x_s + xrow * LROW;
#pragma unroll
      for (int i = 0; i < 8; ++i) {
        int off = xcol * 8 + i * 64;
        f32x4 v0 = *(const f32x4*)(src + off);
        f32x4 v1 = *(const f32x4*)(src + off + 4);
        u16x8 o;
        o[0] = f2bf(v0[0]); o[1] = f2bf(v0[1]); o[2] = f2bf(v0[2]); o[3] = f2bf(v0[3]);
        o[4] = f2bf(v1[0]); o[5] = f2bf(v1[1]); o[6] = f2bf(v1[2]); o[7] = f2bf(v1[3]);
        *(u16x8*)(dst + off) = o;
      }
    }
    __syncthreads();

    unsigned holdp[3][4][2];

#pragma unroll
    for (int p = 0; p < 4; ++p) {
      const int dcol = (p * 8 + wave) * 16 + ln;
      const u16* wrow = W + (size_t)dcol * 1024;

      f32x4 accr[4], accz[4], acchn[4], accxn[4];
#pragma unroll
      for (int mt = 0; mt < 4; ++mt)
#pragma unroll
        for (int j = 0; j < 4; ++j) {
          accr[mt][j] = 0.f; accz[mt][j] = 0.f;
          acchn[mt][j] = 0.f; accxn[mt][j] = 0.f;
        }

#pragma unroll
      for (int kk = 0; kk < 16; ++kk) {
        const int krel = kk * 32 + ks * 8;
        bf16x8 a[4];
#pragma unroll
        for (int mt = 0; mt < 4; ++mt)
          a[mt] = *(const bf16x8*)(h_s + (mt * 16 + ln) * LROW + krel);
        bf16x8 br = *(const bf16x8*)(wrow + krel);
        bf16x8 bz = *(const bf16x8*)(wrow + 512 * 1024 + krel);
        bf16x8 bn = *(const bf16x8*)(wrow + 1024 * 1024 + krel);
#pragma unroll
        for (int mt = 0; mt < 4; ++mt) {
          accr[mt] = MFMA(a[mt], br, accr[mt]);
          accz[mt] = MFMA(a[mt], bz, accz[mt]);
          acchn[mt] = MFMA(a[mt], bn, acchn[mt]);
        }
      }
#pragma unroll
      for (int kk = 0; kk < 16; ++kk) {
        const int krel = kk * 32 + ks * 8;
        bf16x8 a[4];
#pragma unroll
        for (int mt = 0; mt < 4; ++mt)
          a[mt] = *(const bf16x8*)(x_s + (mt * 16 + ln) * LROW + krel);
        bf16x8 br = *(const bf16x8*)(wrow + 512 + krel);
        bf16x8 bz = *(const bf16x8*)(wrow + 512 * 1024 + 512 + krel);
        bf16x8 bn = *(const bf16x8*)(wrow + 1024 * 1024 + 512 + krel);
#pragma unroll
        for (int mt = 0; mt < 4; ++mt) {
          accr[mt] = MFMA(a[mt], br, accr[mt]);
          accz[mt] = MFMA(a[mt], bz, accz[mt]);
          accxn[mt] = MFMA(a[mt], bn, accxn[mt]);
        }
      }

      if (p < 3) {
#pragma unroll
        for (int mt = 0; mt < 4; ++mt)
#pragma unroll
          for (int jp = 0; jp < 2; ++jp) {
            unsigned pk = 0;
#pragma unroll
            for (int jh = 0; jh < 2; ++jh) {
              const int j = jp * 2 + jh;
              const int row = mt * 16 + ks * 4 + j;
              float rr = sigm(accr[mt][j] + b_r[p]);
              float zz = sigm(accz[mt][j] + b_z[p]);
              float nn = tanh_(accxn[mt][j] + b_xn[p] +
                               rr * (acchn[mt][j] + b_hn[p]));
              float hold = bf2f(h_s[row * LROW + dcol]);
              float hnew = (t < len_s[row]) ? ((1.f - zz) * nn + zz * hold) : hold;
              pk |= ((unsigned)f2bf(hnew)) << (16 * jh);
            }
            holdp[p][mt][jp] = pk;
          }
      } else {
        __syncthreads();
#pragma unroll
        for (int pp = 0; pp < 3; ++pp) {
          const int dd = (pp * 8 + wave) * 16 + ln;
#pragma unroll
          for (int mt = 0; mt < 4; ++mt)
#pragma unroll
            for (int jp = 0; jp < 2; ++jp) {
              unsigned pk = holdp[pp][mt][jp];
              const int row = mt * 16 + ks * 4 + jp * 2;
              h_s[row * LROW + dd] = (u16)pk;
              h_s[(row + 1) * LROW + dd] = (u16)(pk >> 16);
            }
        }
#pragma unroll
        for (int mt = 0; mt < 4; ++mt)
#pragma unroll
          for (int j = 0; j < 4; ++j) {
            const int row = mt * 16 + ks * 4 + j;
            float rr = sigm(accr[mt][j] + b_r[3]);
            float zz = sigm(accz[mt][j] + b_z[3]);
            float nn = tanh_(accxn[mt][j] + b_xn[3] +
                             rr * (acchn[mt][j] + b_hn[3]));
            float hold = bf2f(h_s[row * LROW + dcol]);
            float hnew = (t < len_s[row]) ? ((1.f - zz) * nn + zz * hold) : hold;
            h_s[row * LROW + dcol] = f2bf(hnew);
          }
      }
    }
  }

  __syncthreads();
#pragma unroll
  for (int i = 0; i < 8; ++i) {
    int off = xcol * 8 + i * 64;
    u16x8 v = *(const u16x8*)(h_s + xrow * LROW + off);
    __builtin_nontemporal_store(
        v, (u16x8*)(hcat + (size_t)(s0 + xrow) * 1024 + dir * 512 + off));
  }
}

// ---------------------------------------------------------------------------
// MLP GEMM: out[M,N] = act(A[M,K] @ Bw[N,K]^T + bias)
// perm != nullptr: store row goes to perm[row] (undoes the length sort).
// ---------------------------------------------------------------------------
__global__ __launch_bounds__(256) void mlp_gemm(const u16* __restrict__ A,
                                                const u16* __restrict__ Bw,
                                                const float* __restrict__ bias,
                                                const int* __restrict__ perm,
                                                void* __restrict__ out, int M,
                                                int N, int K, int mode) {
  __shared__ u16 As[128 * 64], Bs[128 * 64];
  const int tid = threadIdx.x;
  const int wave = tid >> 6, lane = tid & 63;
  const int ln = lane & 15, ks = lane >> 4;
  const int wm = wave & 1, wn = wave >> 1;
  const int m0 = blockIdx.x * 128, n0 = blockIdx.y * 128;
  f32x4 acc[4][4];
#pragma unroll
  for (int mt = 0; mt < 4; ++mt)
#pragma unroll
    for (int nt = 0; nt < 4; ++nt)
#pragma unroll
      for (int j = 0; j < 4; ++j) acc[mt][nt][j] = 0.f;

  const int r = tid >> 1, hh = tid & 1;
  for (int k0 = 0; k0 < K; k0 += 64) {
    const i32x4* sa = (const i32x4*)(A + (size_t)(m0 + r) * K + k0 + hh * 32);
    const i32x4* sb = (const i32x4*)(Bw + (size_t)(n0 + r) * K + k0 + hh * 32);
    i32x4* da = (i32x4*)(As + r * 64 + hh * 32);
    i32x4* db = (i32x4*)(Bs + r * 64 + hh * 32);
#pragma unroll
    for (int i = 0; i < 4; ++i) da[i] = sa[i];
#pragma unroll
    for (int i = 0; i < 4; ++i) db[i] = sb[i];
    __syncthreads();
#pragma unroll
    for (int kk = 0; kk < 2; ++kk) {
      bf16x8 af[4], bfm[4];
#pragma unroll
      for (int mt = 0; mt < 4; ++mt)
        af[mt] = *(const bf16x8*)(As + (wm * 64 + mt * 16 + ln) * 64 + kk * 32 + ks * 8);
#pragma unroll
      for (int nt = 0; nt < 4; ++nt)
        bfm[nt] = *(const bf16x8*)(Bs + (wn * 64 + nt * 16 + ln) * 64 + kk * 32 + ks * 8);
#pragma unroll
      for (int mt = 0; mt < 4; ++mt)
#pragma unroll
        for (int nt = 0; nt < 4; ++nt) acc[mt][nt] = MFMA(af[mt], bfm[nt], acc[mt][nt]);
    }
    __syncthreads();
  }

#pragma unroll
  for (int nt = 0; nt < 4; ++nt) {
    int col = n0 + wn * 64 + nt * 16 + ln;
    float bv = bias[col];
#pragma unroll
    for (int mt = 0; mt < 4; ++mt)
#pragma unroll
      for (int j = 0; j < 4; ++j) {
        int row = m0 + wm * 64 + mt * 16 + ks * 4 + j;
        float v = acc[mt][nt][j] + bv;
        int orow = perm ? perm[row] : row;
        if (mode) {
          v = fmaxf(v, 0.f);
          ((u16*)out)[(size_t)orow * N + col] = f2bf(v);
        } else {
          ((float*)out)[(size_t)orow * N + col] = v;
        }
      }
  }
}

// ---------------------------------------------------------------------------
extern "C" void kernel_launch(void* const* d_in, const int* in_sizes, int n_in,
                              void* d_out, int out_size, void* d_ws, size_t ws_size,
                              hipStream_t stream) {
  (void)in_sizes; (void)n_in; (void)out_size;
  const float* win = (const float*)d_in[0];
  const int* wlen = (const int*)d_in[1];
  const float* Wih_f = (const float*)d_in[2];
  const float* Whh_f = (const float*)d_in[3];
  const float* bih_f = (const float*)d_in[4];
  const float* bhh_f = (const float*)d_in[5];
  const float* Wih_b = (const float*)d_in[6];
  const float* Whh_b = (const float*)d_in[7];
  const float* bih_b = (const float*)d_in[8];
  const float* bhh_b = (const float*)d_in[9];
  const float* W1 = (const float*)d_in[10];
  const float* b1 = (const float*)d_in[11];
  const float* W2 = (const float*)d_in[12];
  const float* b2 = (const float*)d_in[13];

  const size_t NEED = 4ull * 1572864 + 1048576 + 524288 + 16777216 + 8388608 +
                      402653184ull + 65536;  // +order +rank

  if (ws_size >= NEED) {
    char* ws = (char*)d_ws;
    u16* Wp_f = (u16*)ws;   ws += 1572864;
    u16* Wp_b = (u16*)ws;   ws += 1572864;
    u16* Wihb_f = (u16*)ws; ws += 1572864;
    u16* Wihb_b = (u16*)ws; ws += 1572864;
    u16* W1b = (u16*)ws;    ws += 1048576;
    u16* W2b = (u16*)ws;    ws += 524288;
    u16* hcat = (u16*)ws;   ws += 16777216;
    u16* hidden = (u16*)ws; ws += 8388608;
    int* order = (int*)ws;  ws += 32768;
    int* rank = (int*)ws;   ws += 32768;
    u16* xp = (u16*)ws;     ws += 402653184;

    sort_len<<<1, 1024, 0, stream>>>(wlen, order, rank);
    wrepack<<<384, 256, 0, stream>>>(Whh_f, Wp_f);
    wrepack<<<384, 256, 0, stream>>>(Whh_b, Wp_b);
    cvt_bf16<<<384, 256, 0, stream>>>(Wih_f, Wihb_f, 98304);
    cvt_bf16<<<384, 256, 0, stream>>>(Wih_b, Wihb_b, 98304);
    cvt_bf16<<<256, 256, 0, stream>>>(W1, W1b, 65536);
    cvt_bf16<<<128, 256, 0, stream>>>(W2, W2b, 32768);

    const int SMEM_XP = 128 * LROWA * 2;  // 133,120 B (1 block/CU, 2 wv/SIMD)
    (void)hipFuncSetAttribute((const void*)xp_gemm,
                              hipFuncAttributeMaxDynamicSharedMemorySize, SMEM_XP);
    xp_gemm<<<dim3(64, 8, 2), 512, SMEM_XP, stream>>>(
        win, wlen, order, Wihb_f, Wihb_b, bih_f, bih_b, bhh_f, bhh_b, xp);

    const int SMEM = 2 * 64 * LROW * 2 + 64 * 4 + 16;
    (void)hipFuncSetAttribute((const void*)gru_rec,
                              hipFuncAttributeMaxDynamicSharedMemorySize, SMEM);
    gru_rec<<<256, 1024, SMEM, stream>>>(wlen, order, Wp_f, Wp_b, bhh_f, bhh_b,
                                         xp, hcat);

    mlp_gemm<<<dim3(64, 4), 256, 0, stream>>>(hcat, W1b, b1, nullptr, hidden,
                                              8192, 512, 1024, 1);
    mlp_gemm<<<dim3(64, 4), 256, 0, stream>>>(hidden, W2b, b2, order, d_out,
                                              8192, 512, 512, 0);
  } else {
    char* ws = (char*)d_ws;
    u16* Wcat_f = (u16*)ws;  ws += 3145728;
    u16* Wcat_b = (u16*)ws;  ws += 3145728;
    u16* W1b = (u16*)ws;     ws += 1048576;
    u16* W2b = (u16*)ws;     ws += 524288;
    u16* hcat = (u16*)ws;    ws += 16777216;
    u16* hidden = (u16*)ws;  ws += 8388608;

    build_wcat<<<768, 256, 0, stream>>>(Whh_f, Wih_f, Wcat_f);
    build_wcat<<<768, 256, 0, stream>>>(Whh_b, Wih_b, Wcat_b);
    cvt_bf16<<<256, 256, 0, stream>>>(W1, W1b, 65536);
    cvt_bf16<<<128, 256, 0, stream>>>(W2, W2b, 32768);

    const int SMEM = 2 * 64 * LROW * 2 + 64 * 4 + 16;
    (void)hipFuncSetAttribute((const void*)gru_persistent,
                              hipFuncAttributeMaxDynamicSharedMemorySize, SMEM);
    gru_persistent<<<256, 512, SMEM, stream>>>(win, wlen, Wcat_f, Wcat_b, bih_f,
                                               bhh_f, bih_b, bhh_b, hcat);

    mlp_gemm<<<dim3(64, 4), 256, 0, stream>>>(hcat, W1b, b1, nullptr, hidden,
                                              8192, 512, 1024, 1);
    mlp_gemm<<<dim3(64, 4), 256, 0, stream>>>(hidden, W2b, b2, nullptr, d_out,
                                              8192, 512, 512, 0);
  }
}

// Round 14
// 1839.530 us; speedup vs baseline: 3.2891x; 1.1092x over previous
//
#include <hip/hip_runtime.h>

typedef unsigned short u16;
typedef __attribute__((ext_vector_type(4))) float f32x4;
typedef __attribute__((ext_vector_type(8))) __bf16 bf16x8;
typedef __attribute__((ext_vector_type(8))) u16 u16x8;
typedef __attribute__((ext_vector_type(4))) u16 u16x4;
typedef __attribute__((ext_vector_type(4))) int i32x4;

#define MFMA(a, b, c) __builtin_amdgcn_mfma_f32_16x16x32_bf16(a, b, c, 0, 0, 0)

__device__ __forceinline__ u16 f2bf(float f) {
  union { float f; unsigned u; } v; v.f = f;
  unsigned r = v.u + 0x7FFFu + ((v.u >> 16) & 1u);
  return (u16)(r >> 16);
}
__device__ __forceinline__ float bf2f(u16 b) {
  union { unsigned u; float f; } v; v.u = ((unsigned)b) << 16; return v.f;
}
__device__ __forceinline__ float sigm(float x) { return 1.f / (1.f + __expf(-x)); }
__device__ __forceinline__ float tanh_(float x) {
  float e = __expf(-2.f * fabsf(x));
  float r = (1.f - e) / (1.f + e);
  return x < 0.f ? -r : r;
}

// xp layout (UNSORTED, sample-indexed): plane = (dir*8 + t)*96 + g (g=col>>4).
// Within plane: offset = (s>>2)*64 + (col&15)*4 + (s&3). GSTRIDE elems/plane.
#define GSTRIDE 131072

// ---------------------------------------------------------------------------
__global__ __launch_bounds__(256) void cvt_bf16(const float* __restrict__ src,
                                                u16* __restrict__ dst, int n8) {
  int i = blockIdx.x * 256 + threadIdx.x;
  if (i >= n8) return;
  int e = i * 8;
  u16x8 o;
#pragma unroll
  for (int j = 0; j < 8; ++j) o[j] = f2bf(src[e + j]);
  *(u16x8*)(dst + e) = o;
}

// ---------------------------------------------------------------------------
// wrepack: Whh (f32 1536x512) -> fragment-ordered bf16 Wp so one wave weight
// load in gru_rec is 1KB CONTIGUOUS (the isolated lever from the sorted
// family: scattered dcol*512 loads waste half of every 128B line).
// Wp index: (((q*16 + kk)*3 + gate)*64 + lane)*8, lane = ks*16+ln, holding
// Whh[gate*512 + q*16 + ln][kk*32 + ks*8 + e].
// ---------------------------------------------------------------------------
__global__ __launch_bounds__(256) void wrepack(const float* __restrict__ Whh,
                                               u16* __restrict__ Wp) {
  int i = blockIdx.x * 256 + threadIdx.x;  // one u16x8 per thread
  if (i >= 98304) return;
  int q = i / 3072;
  int r1 = i % 3072;
  int kk = r1 / 192;
  int r2 = r1 % 192;
  int g = r2 / 64;
  int r3 = r2 % 64;
  int ks = r3 >> 4, ln = r3 & 15;
  const float* src =
      Whh + (size_t)(g * 512 + q * 16 + ln) * 512 + kk * 32 + ks * 8;
  u16x8 o;
#pragma unroll
  for (int j = 0; j < 8; ++j) o[j] = f2bf(src[j]);
  *(u16x8*)(Wp + (size_t)i * 8) = o;
}

// ---------------------------------------------------------------------------
// xp_gemm (R5-measured design, unchanged): one block = 128 CONTIGUOUS rows
// (16 consecutive samples x 8 t) x FULL N=1536. A staged once in 133KB LDS;
// B (Wih bf16, 1.5MB) read per-fragment from L2. Grid (512, 2=dir).
// Biases bih (+bhh for r,z) folded into xp. Dense sample-indexed stores.
// ---------------------------------------------------------------------------
#define LROWA 520  // LDS A row stride (bf16 elems)

__global__ __launch_bounds__(256)
__attribute__((amdgpu_waves_per_eu(1, 1))) void xp_gemm(
    const float* __restrict__ win, const int* __restrict__ wlen,
    const u16* __restrict__ Wihb_f, const u16* __restrict__ Wihb_b,
    const float* __restrict__ bih_f, const float* __restrict__ bih_b,
    const float* __restrict__ bhh_f, const float* __restrict__ bhh_b,
    u16* __restrict__ xp) {
  extern __shared__ char smem[];
  u16* As = (u16*)smem;  // [128][LROWA]

  const int dir = blockIdx.y;
  const u16* Wb = dir ? Wihb_b : Wihb_f;
  const float* bih = dir ? bih_b : bih_f;
  const float* bhh = dir ? bhh_b : bhh_f;

  const int tid = threadIdx.x;
  const int bx = blockIdx.x;

  // ---- stage A: 128 gathered rows (16 consecutive samples), f32 -> bf16 ----
  {
    const int r = tid >> 1, hh = tid & 1;
    const int m = bx * 128 + r;
    const int s = m >> 3, tt = m & 7;
    const int wl = wlen[s];
    const int len = dir ? (wl / 2 + 1) : ((wl - 1) / 2 + 1);
    const int widx = dir ? (6 + len - tt) : (8 - len + tt);  // in [0,14]
    const float* src = win + ((size_t)s * 15 + widx) * 512 + hh * 256;
    u16* dst = As + r * LROWA + hh * 256;
#pragma unroll
    for (int i = 0; i < 32; ++i) {
      f32x4 v0 = *(const f32x4*)(src + i * 8);
      f32x4 v1 = *(const f32x4*)(src + i * 8 + 4);
      u16x8 o;
      o[0] = f2bf(v0[0]); o[1] = f2bf(v0[1]); o[2] = f2bf(v0[2]); o[3] = f2bf(v0[3]);
      o[4] = f2bf(v1[0]); o[5] = f2bf(v1[1]); o[6] = f2bf(v1[2]); o[7] = f2bf(v1[3]);
      *(u16x8*)(dst + i * 8) = o;
    }
  }
  __syncthreads();

  const int wave = tid >> 6;
  const int lane = tid & 63;
  const int ln = lane & 15;
  const int ks = lane >> 4;

#pragma unroll 1
  for (int g = 0; g < 6; ++g) {
    const int c0 = wave * 24 + g * 4;

    f32x4 acc[8][4];
#pragma unroll
    for (int mt = 0; mt < 8; ++mt)
#pragma unroll
      for (int u = 0; u < 4; ++u)
#pragma unroll
        for (int j = 0; j < 4; ++j) acc[mt][u][j] = 0.f;

#pragma unroll
    for (int kk = 0; kk < 16; ++kk) {
      const int krel = kk * 32 + ks * 8;
      bf16x8 a[8];
#pragma unroll
      for (int mt = 0; mt < 8; ++mt)
        a[mt] = *(const bf16x8*)(As + (mt * 16 + ln) * LROWA + krel);
      bf16x8 b[4];
#pragma unroll
      for (int u = 0; u < 4; ++u)
        b[u] = *(const bf16x8*)(Wb + (size_t)((c0 + u) * 16 + ln) * 512 + krel);
#pragma unroll
      for (int mt = 0; mt < 8; ++mt)
#pragma unroll
        for (int u = 0; u < 4; ++u) acc[mt][u] = MFMA(a[mt], b[u], acc[mt][u]);
    }

    // epilogue: fold biases, store to sample-indexed xp layout
#pragma unroll
    for (int u = 0; u < 4; ++u) {
      const int col = (c0 + u) * 16 + ln;
      const float bv = bih[col] + (col < 1024 ? bhh[col] : 0.f);
#pragma unroll
      for (int mt = 0; mt < 8; ++mt)
#pragma unroll
        for (int j = 0; j < 4; ++j) {
          const int rowm = bx * 128 + mt * 16 + ks * 4 + j;
          const int s = rowm >> 3, t = rowm & 7;
          const size_t idx = ((size_t)(dir * 8 + t) * 96 + (c0 + u)) * GSTRIDE +
                             (size_t)(s >> 2) * 64 + ln * 4 + (s & 3);
          xp[idx] = f2bf(acc[mt][u][j] + bv);
        }
    }
  }
}

// ---------------------------------------------------------------------------
// gru_rec (R5 structure + wrepack): 256 blocks x 1024 threads (16 waves, 4
// waves/SIMD). 2 N-half passes x 16 waves x 16 cols; h double-buffered in
// LDS (133KB, 1 block/CU); ONE barrier per step; xp prefetched pre-K-loop
// as 12 vectorized u16x4 loads. ONLY change vs R5 (1166us measured):
// weights via fragment-ordered Wp -> 1KB CONTIGUOUS per wave K-step load
// (was 16 scattered 64B segments wasting half of every line).
// ---------------------------------------------------------------------------
#define LROW 520  // padded LDS row stride (bf16) to break bank conflicts

__global__ __launch_bounds__(1024)
__attribute__((amdgpu_waves_per_eu(4, 4))) void gru_rec(
    const int* __restrict__ wlen, const u16* __restrict__ Wp_f,
    const u16* __restrict__ Wp_b, const float* __restrict__ bhh_f,
    const float* __restrict__ bhh_b, const u16* __restrict__ xp,
    u16* __restrict__ hcat) {
  extern __shared__ char smem[];
  u16* hb0 = (u16*)smem;       // [64][LROW]
  u16* hb1 = hb0 + 64 * LROW;  // [64][LROW]
  int* len_s = (int*)(hb1 + 64 * LROW);
  int* bmax_s = len_s + 64;

  const int dir = blockIdx.x & 1;
  const int grp = blockIdx.x >> 1;
  const int s0 = grp * 64;
  const u16* W = dir ? Wp_b : Wp_f;
  const float* bhh = dir ? bhh_b : bhh_f;

  const int tid = threadIdx.x;
  const int wave = tid >> 6;  // 0..15
  const int lane = tid & 63;
  const int ln = lane & 15;
  const int ks = lane >> 4;  // 0..3

  // ---- init: zero hb0, lengths + block max ----
  if (tid == 0) *bmax_s = 0;
  for (int i = tid; i < 64 * LROW / 8; i += 1024) ((u16x8*)hb0)[i] = (u16x8)0;
  __syncthreads();
  if (tid < 64) {
    int wl = wlen[s0 + tid];
    int len = dir ? (wl / 2 + 1) : ((wl - 1) / 2 + 1);
    len_s[tid] = len;
    atomicMax(bmax_s, len);
  }
  __syncthreads();
  const int bmax = *bmax_s;

  // only the n-gate recurrent bias survives (r,z biases folded into xp)
  float b_hn[2];
#pragma unroll
  for (int p = 0; p < 2; ++p) b_hn[p] = bhh[1024 + (p * 16 + wave) * 16 + ln];

  for (int t = 0; t < bmax; ++t) {
    u16* h_cur = (t & 1) ? hb1 : hb0;
    u16* h_nxt = (t & 1) ? hb0 : hb1;
    const u16* xpt = xp + (size_t)(dir * 8 + t) * 96 * GSTRIDE;

#pragma unroll
    for (int p = 0; p < 2; ++p) {
      const int q = p * 16 + wave;  // gate-col chunk 0..31
      const int dcol = q * 16 + ln;
      const u16* wq = W + (size_t)q * 24576 + lane * 8;  // fragment-ordered

      // ---- prefetch xp for this pass: 12 vector loads, hidden by K-loop ----
      u16x4 xr4[4], xz4[4], xn4[4];
#pragma unroll
      for (int mt = 0; mt < 4; ++mt) {
        const size_t off = (size_t)((s0 >> 2) + mt * 4 + ks) * 64 + ln * 4;
        xr4[mt] = *(const u16x4*)(xpt + (size_t)q * GSTRIDE + off);
        xz4[mt] = *(const u16x4*)(xpt + (size_t)(32 + q) * GSTRIDE + off);
        xn4[mt] = *(const u16x4*)(xpt + (size_t)(64 + q) * GSTRIDE + off);
      }

      f32x4 accr[4], accz[4], acchn[4];
#pragma unroll
      for (int mt = 0; mt < 4; ++mt)
#pragma unroll
        for (int j = 0; j < 4; ++j) {
          accr[mt][j] = 0.f; accz[mt][j] = 0.f; acchn[mt][j] = 0.f;
        }

#pragma unroll
      for (int kk = 0; kk < 16; ++kk) {
        const int krel = kk * 32 + ks * 8;
        bf16x8 a[4];
#pragma unroll
        for (int mt = 0; mt < 4; ++mt)
          a[mt] = *(const bf16x8*)(h_cur + (mt * 16 + ln) * LROW + krel);
        const u16* wk = wq + kk * 1536;
        bf16x8 br = *(const bf16x8*)(wk);  // contiguous 1KB/wave
        bf16x8 bz = *(const bf16x8*)(wk + 512);
        bf16x8 bn = *(const bf16x8*)(wk + 1024);
#pragma unroll
        for (int mt = 0; mt < 4; ++mt) {
          accr[mt] = MFMA(a[mt], br, accr[mt]);
          accz[mt] = MFMA(a[mt], bz, accz[mt]);
          acchn[mt] = MFMA(a[mt], bn, acchn[mt]);
        }
      }

      // epilogue: prefetched xp + nonlinearity; write to the OTHER buffer
#pragma unroll
      for (int mt = 0; mt < 4; ++mt)
#pragma unroll
        for (int j = 0; j < 4; ++j) {
          const int row = mt * 16 + ks * 4 + j;
          float xr = bf2f(xr4[mt][j]);
          float xz = bf2f(xz4[mt][j]);
          float xn = bf2f(xn4[mt][j]);
          float rr = sigm(accr[mt][j] + xr);
          float zz = sigm(accz[mt][j] + xz);
          float nn = tanh_(xn + rr * (acchn[mt][j] + b_hn[p]));
          float hold = bf2f(h_cur[row * LROW + dcol]);
          float hnew = (t < len_s[row]) ? ((1.f - zz) * nn + zz * hold) : hold;
          h_nxt[row * LROW + dcol] = f2bf(hnew);
        }
    }  // passes
    __syncthreads();  // h_nxt complete before it becomes h_cur
  }    // t

  // ---- write final h to hcat[s][dir*512 + k] ----
  const u16* hf = (bmax & 1) ? hb1 : hb0;
  const int xrow = tid >> 4;  // 0..63
  const int xcol = tid & 15;  // 0..15
#pragma unroll
  for (int i = 0; i < 4; ++i) {
    int off = (i * 16 + xcol) * 8;
    u16x8 v = *(const u16x8*)(hf + xrow * LROW + off);
    __builtin_nontemporal_store(
        v, (u16x8*)(hcat + (size_t)(s0 + xrow) * 1024 + dir * 512 + off));
  }
}

// ---------------------------------------------------------------------------
// FALLBACK path (ws too small): round-2 fused kernel.
// ---------------------------------------------------------------------------
__global__ __launch_bounds__(256) void build_wcat(const float* __restrict__ Whh,
                                                  const float* __restrict__ Wih,
                                                  u16* __restrict__ Wcat) {
  int i = blockIdx.x * 256 + threadIdx.x;
  if (i >= 1536 * 1024 / 8) return;
  int e = i * 8;
  int g = e >> 10, k = e & 1023;
  const float* src = (k < 512) ? (Whh + g * 512 + k) : (Wih + g * 512 + (k - 512));
  u16x8 o;
#pragma unroll
  for (int j = 0; j < 8; ++j) o[j] = f2bf(src[j]);
  *(u16x8*)(Wcat + e) = o;
}

__global__ __launch_bounds__(512)
__attribute__((amdgpu_waves_per_eu(2, 2))) void gru_persistent(
    const float* __restrict__ win, const int* __restrict__ wlen,
    const u16* __restrict__ Wcat_f, const u16* __restrict__ Wcat_b,
    const float* __restrict__ bih_f, const float* __restrict__ bhh_f,
    const float* __restrict__ bih_b, const float* __restrict__ bhh_b,
    u16* __restrict__ hcat) {
  extern __shared__ char smem[];
  u16* h_s = (u16*)smem;
  u16* x_s = (u16*)(smem + 64 * LROW * 2);
  int* len_s = (int*)(smem + 2 * 64 * LROW * 2);
  int* bmax_s = len_s + 64;

  const int dir = blockIdx.x & 1;
  const int grp = blockIdx.x >> 1;
  const int s0 = grp * 64;
  const u16* W = dir ? Wcat_b : Wcat_f;
  const float* bih = dir ? bih_b : bih_f;
  const float* bhh = dir ? bhh_b : bhh_f;

  const int tid = threadIdx.x;
  const int wave = tid >> 6;
  const int lane = tid & 63;
  const int ln = lane & 15;
  const int ks = lane >> 4;

  if (tid == 0) *bmax_s = 0;
  for (int i = tid; i < 64 * LROW / 8; i += 512) ((u16x8*)h_s)[i] = (u16x8)0;
  __syncthreads();
  if (tid < 64) {
    int wl = wlen[s0 + tid];
    int len = dir ? (wl / 2 + 1) : ((wl - 1) / 2 + 1);
    len_s[tid] = len;
    atomicMax(bmax_s, len);
  }
  __syncthreads();
  const int bmax = *bmax_s;

  float b_r[4], b_z[4], b_xn[4], b_hn[4];
#pragma unroll
  for (int p = 0; p < 4; ++p) {
    int d = (p * 8 + wave) * 16 + ln;
    b_r[p] = bih[d] + bhh[d];
    b_z[p] = bih[512 + d] + bhh[512 + d];
    b_xn[p] = bih[1024 + d];
    b_hn[p] = bhh[1024 + d];
  }

  const int xrow = tid >> 3;
  const int xcol = tid & 7;
  const int mylen = len_s[xrow];
  const long xbase = (long)(s0 + xrow) * 15 + (dir ? (6 + mylen) : (8 - mylen));

  for (int t = 0; t < bmax; ++t) {
    {
      long rowidx = dir ? (xbase - t) : (xbase + t);
      const float* src = win + rowidx * 512;
      u16* dst = x_s + xrow * LROW;
#pragma unroll
      for (int i = 0; i < 8; ++i) {
        int off = xcol * 8 + i * 64;
        f32x4 v0 = *(const f32x4*)(src + off);
        f32x4 v1 = *(const f32x4*)(src + off + 4);
        u16x8 o;
        o[0] = f2bf(v0[0]); o[1] = f2bf(v0[1]); o[2] = f2bf(v0[2]); o[3] = f2bf(v0[3]);
        o[4] = f2bf(v1[0]); o[5] = f2bf(v1[1]); o[6] = f2bf(v1[2]); o[7] = f2bf(v1[3]);
        *(u16x8*)(dst + off) = o;
      }
    }
    __syncthreads();

    unsigned holdp[3][4][2];

#pragma unroll
    for (int p = 0; p < 4; ++p) {
      const int dcol = (p * 8 + wave) * 16 + ln;
      const u16* wrow = W + (size_t)dcol * 1024;

      f32x4 accr[4], accz[4], acchn[4], accxn[4];
#pragma unroll
      for (int mt = 0; mt < 4; ++mt)
#pragma unroll
        for (int j = 0; j < 4; ++j) {
          accr[mt][j] = 0.f; accz[mt][j] = 0.f;
          acchn[mt][j] = 0.f; accxn[mt][j] = 0.f;
        }

#pragma unroll
      for (int kk = 0; kk < 16; ++kk) {
        const int krel = kk * 32 + ks * 8;
        bf16x8 a[4];
#pragma unroll
        for (int mt = 0; mt < 4; ++mt)
          a[mt] = *(const bf16x8*)(h_s + (mt * 16 + ln) * LROW + krel);
        bf16x8 br = *(const bf16x8*)(wrow + krel);
        bf16x8 bz = *(const bf16x8*)(wrow + 512 * 1024 + krel);
        bf16x8 bn = *(const bf16x8*)(wrow + 1024 * 1024 + krel);
#pragma unroll
        for (int mt = 0; mt < 4; ++mt) {
          accr[mt] = MFMA(a[mt], br, accr[mt]);
          accz[mt] = MFMA(a[mt], bz, accz[mt]);
          acchn[mt] = MFMA(a[mt], bn, acchn[mt]);
        }
      }
#pragma unroll
      for (int kk = 0; kk < 16; ++kk) {
        const int krel = kk * 32 + ks * 8;
        bf16x8 a[4];
#pragma unroll
        for (int mt = 0; mt < 4; ++mt)
          a[mt] = *(const bf16x8*)(x_s + (mt * 16 + ln) * LROW + krel);
        bf16x8 br = *(const bf16x8*)(wrow + 512 + krel);
        bf16x8 bz = *(const bf16x8*)(wrow + 512 * 1024 + 512 + krel);
        bf16x8 bn = *(const bf16x8*)(wrow + 1024 * 1024 + 512 + krel);
#pragma unroll
        for (int mt = 0; mt < 4; ++mt) {
          accr[mt] = MFMA(a[mt], br, accr[mt]);
          accz[mt] = MFMA(a[mt], bz, accz[mt]);
          accxn[mt] = MFMA(a[mt], bn, accxn[mt]);
        }
      }

      if (p < 3) {
#pragma unroll
        for (int mt = 0; mt < 4; ++mt)
#pragma unroll
          for (int jp = 0; jp < 2; ++jp) {
            unsigned pk = 0;
#pragma unroll
            for (int jh = 0; jh < 2; ++jh) {
              const int j = jp * 2 + jh;
              const int row = mt * 16 + ks * 4 + j;
              float rr = sigm(accr[mt][j] + b_r[p]);
              float zz = sigm(accz[mt][j] + b_z[p]);
              float nn = tanh_(accxn[mt][j] + b_xn[p] +
                               rr * (acchn[mt][j] + b_hn[p]));
              float hold = bf2f(h_s[row * LROW + dcol]);
              float hnew = (t < len_s[row]) ? ((1.f - zz) * nn + zz * hold) : hold;
              pk |= ((unsigned)f2bf(hnew)) << (16 * jh);
            }
            holdp[p][mt][jp] = pk;
          }
      } else {
        __syncthreads();
#pragma unroll
        for (int pp = 0; pp < 3; ++pp) {
          const int dd = (pp * 8 + wave) * 16 + ln;
#pragma unroll
          for (int mt = 0; mt < 4; ++mt)
#pragma unroll
            for (int jp = 0; jp < 2; ++jp) {
              unsigned pk = holdp[pp][mt][jp];
              const int row = mt * 16 + ks * 4 + jp * 2;
              h_s[row * LROW + dd] = (u16)pk;
              h_s[(row + 1) * LROW + dd] = (u16)(pk >> 16);
            }
        }
#pragma unroll
        for (int mt = 0; mt < 4; ++mt)
#pragma unroll
          for (int j = 0; j < 4; ++j) {
            const int row = mt * 16 + ks * 4 + j;
            float rr = sigm(accr[mt][j] + b_r[3]);
            float zz = sigm(accz[mt][j] + b_z[3]);
            float nn = tanh_(accxn[mt][j] + b_xn[3] +
                             rr * (acchn[mt][j] + b_hn[3]));
            float hold = bf2f(h_s[row * LROW + dcol]);
            float hnew = (t < len_s[row]) ? ((1.f - zz) * nn + zz * hold) : hold;
            h_s[row * LROW + dcol] = f2bf(hnew);
          }
      }
    }
  }

  __syncthreads();
#pragma unroll
  for (int i = 0; i < 8; ++i) {
    int off = xcol * 8 + i * 64;
    u16x8 v = *(const u16x8*)(h_s + xrow * LROW + off);
    __builtin_nontemporal_store(
        v, (u16x8*)(hcat + (size_t)(s0 + xrow) * 1024 + dir * 512 + off));
  }
}

// ---------------------------------------------------------------------------
// MLP GEMM: out[M,N] = act(A[M,K] @ Bw[N,K]^T + bias)
// ---------------------------------------------------------------------------
__global__ __launch_bounds__(256) void mlp_gemm(const u16* __restrict__ A,
                                                const u16* __restrict__ Bw,
                                                const float* __restrict__ bias,
                                                void* __restrict__ out, int M,
                                                int N, int K, int mode) {
  __shared__ u16 As[128 * 64], Bs[128 * 64];
  const int tid = threadIdx.x;
  const int wave = tid >> 6, lane = tid & 63;
  const int ln = lane & 15, ks = lane >> 4;
  const int wm = wave & 1, wn = wave >> 1;
  const int m0 = blockIdx.x * 128, n0 = blockIdx.y * 128;
  f32x4 acc[4][4];
#pragma unroll
  for (int mt = 0; mt < 4; ++mt)
#pragma unroll
    for (int nt = 0; nt < 4; ++nt)
#pragma unroll
      for (int j = 0; j < 4; ++j) acc[mt][nt][j] = 0.f;

  const int r = tid >> 1, hh = tid & 1;
  for (int k0 = 0; k0 < K; k0 += 64) {
    const i32x4* sa = (const i32x4*)(A + (size_t)(m0 + r) * K + k0 + hh * 32);
    const i32x4* sb = (const i32x4*)(Bw + (size_t)(n0 + r) * K + k0 + hh * 32);
    i32x4* da = (i32x4*)(As + r * 64 + hh * 32);
    i32x4* db = (i32x4*)(Bs + r * 64 + hh * 32);
#pragma unroll
    for (int i = 0; i < 4; ++i) da[i] = sa[i];
#pragma unroll
    for (int i = 0; i < 4; ++i) db[i] = sb[i];
    __syncthreads();
#pragma unroll
    for (int kk = 0; kk < 2; ++kk) {
      bf16x8 af[4], bfm[4];
#pragma unroll
      for (int mt = 0; mt < 4; ++mt)
        af[mt] = *(const bf16x8*)(As + (wm * 64 + mt * 16 + ln) * 64 + kk * 32 + ks * 8);
#pragma unroll
      for (int nt = 0; nt < 4; ++nt)
        bfm[nt] = *(const bf16x8*)(Bs + (wn * 64 + nt * 16 + ln) * 64 + kk * 32 + ks * 8);
#pragma unroll
      for (int mt = 0; mt < 4; ++mt)
#pragma unroll
        for (int nt = 0; nt < 4; ++nt) acc[mt][nt] = MFMA(af[mt], bfm[nt], acc[mt][nt]);
    }
    __syncthreads();
  }

#pragma unroll
  for (int nt = 0; nt < 4; ++nt) {
    int col = n0 + wn * 64 + nt * 16 + ln;
    float bv = bias[col];
#pragma unroll
    for (int mt = 0; mt < 4; ++mt)
#pragma unroll
      for (int j = 0; j < 4; ++j) {
        int row = m0 + wm * 64 + mt * 16 + ks * 4 + j;
        float v = acc[mt][nt][j] + bv;
        if (mode) {
          v = fmaxf(v, 0.f);
          ((u16*)out)[(size_t)row * N + col] = f2bf(v);
        } else {
          ((float*)out)[(size_t)row * N + col] = v;
        }
      }
  }
}

// ---------------------------------------------------------------------------
extern "C" void kernel_launch(void* const* d_in, const int* in_sizes, int n_in,
                              void* d_out, int out_size, void* d_ws, size_t ws_size,
                              hipStream_t stream) {
  (void)in_sizes; (void)n_in; (void)out_size;
  const float* win = (const float*)d_in[0];
  const int* wlen = (const int*)d_in[1];
  const float* Wih_f = (const float*)d_in[2];
  const float* Whh_f = (const float*)d_in[3];
  const float* bih_f = (const float*)d_in[4];
  const float* bhh_f = (const float*)d_in[5];
  const float* Wih_b = (const float*)d_in[6];
  const float* Whh_b = (const float*)d_in[7];
  const float* bih_b = (const float*)d_in[8];
  const float* bhh_b = (const float*)d_in[9];
  const float* W1 = (const float*)d_in[10];
  const float* b1 = (const float*)d_in[11];
  const float* W2 = (const float*)d_in[12];
  const float* b2 = (const float*)d_in[13];

  const size_t NEED = 4ull * 1572864 + 1048576 + 524288 + 16777216 + 8388608 +
                      402653184ull;

  if (ws_size >= NEED) {
    char* ws = (char*)d_ws;
    u16* Wp_f = (u16*)ws;   ws += 1572864;
    u16* Wp_b = (u16*)ws;   ws += 1572864;
    u16* Wihb_f = (u16*)ws; ws += 1572864;
    u16* Wihb_b = (u16*)ws; ws += 1572864;
    u16* W1b = (u16*)ws;    ws += 1048576;
    u16* W2b = (u16*)ws;    ws += 524288;
    u16* hcat = (u16*)ws;   ws += 16777216;
    u16* hidden = (u16*)ws; ws += 8388608;
    u16* xp = (u16*)ws;     ws += 402653184;

    wrepack<<<384, 256, 0, stream>>>(Whh_f, Wp_f);
    wrepack<<<384, 256, 0, stream>>>(Whh_b, Wp_b);
    cvt_bf16<<<384, 256, 0, stream>>>(Wih_f, Wihb_f, 98304);
    cvt_bf16<<<384, 256, 0, stream>>>(Wih_b, Wihb_b, 98304);
    cvt_bf16<<<256, 256, 0, stream>>>(W1, W1b, 65536);
    cvt_bf16<<<128, 256, 0, stream>>>(W2, W2b, 32768);

    const int SMEM_XP = 128 * LROWA * 2;  // 133,120 B
    (void)hipFuncSetAttribute((const void*)xp_gemm,
                              hipFuncAttributeMaxDynamicSharedMemorySize, SMEM_XP);
    xp_gemm<<<dim3(512, 2), 256, SMEM_XP, stream>>>(
        win, wlen, Wihb_f, Wihb_b, bih_f, bih_b, bhh_f, bhh_b, xp);

    const int SMEM = 2 * 64 * LROW * 2 + 64 * 4 + 16;
    (void)hipFuncSetAttribute((const void*)gru_rec,
                              hipFuncAttributeMaxDynamicSharedMemorySize, SMEM);
    gru_rec<<<256, 1024, SMEM, stream>>>(wlen, Wp_f, Wp_b, bhh_f, bhh_b, xp,
                                         hcat);

    mlp_gemm<<<dim3(64, 4), 256, 0, stream>>>(hcat, W1b, b1, hidden, 8192, 512,
                                              1024, 1);
    mlp_gemm<<<dim3(64, 4), 256, 0, stream>>>(hidden, W2b, b2, d_out, 8192, 512,
                                              512, 0);
  } else {
    char* ws = (char*)d_ws;
    u16* Wcat_f = (u16*)ws;  ws += 3145728;
    u16* Wcat_b = (u16*)ws;  ws += 3145728;
    u16* W1b = (u16*)ws;     ws += 1048576;
    u16* W2b = (u16*)ws;     ws += 524288;
    u16* hcat = (u16*)ws;    ws += 16777216;
    u16* hidden = (u16*)ws;  ws += 8388608;

    build_wcat<<<768, 256, 0, stream>>>(Whh_f, Wih_f, Wcat_f);
    build_wcat<<<768, 256, 0, stream>>>(Whh_b, Wih_b, Wcat_b);
    cvt_bf16<<<256, 256, 0, stream>>>(W1, W1b, 65536);
    cvt_bf16<<<128, 256, 0, stream>>>(W2, W2b, 32768);

    const int SMEM = 2 * 64 * LROW * 2 + 64 * 4 + 16;
    (void)hipFuncSetAttribute((const void*)gru_persistent,
                              hipFuncAttributeMaxDynamicSharedMemorySize, SMEM);
    gru_persistent<<<256, 512, SMEM, stream>>>(win, wlen, Wcat_f, Wcat_b, bih_f,
                                               bhh_f, bih_b, bhh_b, hcat);

    mlp_gemm<<<dim3(64, 4), 256, 0, stream>>>(hcat, W1b, b1, hidden, 8192, 512,
                                              1024, 1);
    mlp_gemm<<<dim3(64, 4), 256, 0, stream>>>(hidden, W2b, b2, d_out, 8192, 512,
                                              512, 0);
  }
}

// Round 15
// 1795.865 us; speedup vs baseline: 3.3690x; 1.0243x over previous
//
#include <hip/hip_runtime.h>

typedef unsigned short u16;
typedef __attribute__((ext_vector_type(4))) float f32x4;
typedef __attribute__((ext_vector_type(8))) __bf16 bf16x8;
typedef __attribute__((ext_vector_type(8))) u16 u16x8;
typedef __attribute__((ext_vector_type(4))) u16 u16x4;
typedef __attribute__((ext_vector_type(4))) int i32x4;

#define MFMA(a, b, c) __builtin_amdgcn_mfma_f32_16x16x32_bf16(a, b, c, 0, 0, 0)

__device__ __forceinline__ u16 f2bf(float f) {
  union { float f; unsigned u; } v; v.f = f;
  unsigned r = v.u + 0x7FFFu + ((v.u >> 16) & 1u);
  return (u16)(r >> 16);
}
__device__ __forceinline__ float bf2f(u16 b) {
  union { unsigned u; float f; } v; v.u = ((unsigned)b) << 16; return v.f;
}
__device__ __forceinline__ float sigm(float x) { return 1.f / (1.f + __expf(-x)); }
__device__ __forceinline__ float tanh_(float x) {
  float e = __expf(-2.f * fabsf(x));
  float r = (1.f - e) / (1.f + e);
  return x < 0.f ? -r : r;
}

// xp layout (sample-indexed): plane = (dir*8 + t)*96 + g (g=col>>4).
// Within plane: offset = (s>>2)*64 + (col&15)*4 + (s&3). GSTRIDE elems/plane.
// Quad (s>>2) owns one contiguous 128B line per plane -> quad-granular
// permutation keeps all loads/stores full-line dense.
#define GSTRIDE 131072

// ---------------------------------------------------------------------------
__global__ __launch_bounds__(256) void cvt_bf16(const float* __restrict__ src,
                                                u16* __restrict__ dst, int n8) {
  int i = blockIdx.x * 256 + threadIdx.x;
  if (i >= n8) return;
  int e = i * 8;
  u16x8 o;
#pragma unroll
  for (int j = 0; j < 8; ++j) o[j] = f2bf(src[e + j]);
  *(u16x8*)(dst + e) = o;
}

// ---------------------------------------------------------------------------
// wrepack: Whh (f32 1536x512) -> fragment-ordered bf16 Wp (1KB contiguous
// per wave K-step load in gru_rec).
// ---------------------------------------------------------------------------
__global__ __launch_bounds__(256) void wrepack(const float* __restrict__ Whh,
                                               u16* __restrict__ Wp) {
  int i = blockIdx.x * 256 + threadIdx.x;  // one u16x8 per thread
  if (i >= 98304) return;
  int q = i / 3072;
  int r1 = i % 3072;
  int kk = r1 / 192;
  int r2 = r1 % 192;
  int g = r2 / 64;
  int r3 = r2 % 64;
  int ks = r3 >> 4, ln = r3 & 15;
  const float* src =
      Whh + (size_t)(g * 512 + q * 16 + ln) * 512 + kk * 32 + ks * 8;
  u16x8 o;
#pragma unroll
  for (int j = 0; j < 8; ++j) o[j] = f2bf(src[j]);
  *(u16x8*)(Wp + (size_t)i * 8) = o;
}

// ---------------------------------------------------------------------------
// sort_quads: counting-sort QUADS (4 consecutive samples) by max window_len.
// len(wl) is monotone in wl for both dirs, so max-wl quad key sorts both.
// qorder[slot] = quad id. Quad granularity keeps xp's 128B quad-lines intact
// (the round-7 lesson: sub-line permutation causes RMW write amplification).
// ---------------------------------------------------------------------------
__global__ __launch_bounds__(1024) void sort_quads(const int* __restrict__ wlen,
                                                   int* __restrict__ qorder) {
  __shared__ int cnt[16];
  __shared__ int off[16];
  const int tid = threadIdx.x;
  if (tid < 16) cnt[tid] = 0;
  __syncthreads();
  for (int q = tid; q < 2048; q += 1024) {
    int m = max(max(wlen[q * 4], wlen[q * 4 + 1]),
                max(wlen[q * 4 + 2], wlen[q * 4 + 3]));
    atomicAdd(&cnt[m - 1], 1);
  }
  __syncthreads();
  if (tid == 0) {
    int run = 0;
#pragma unroll
    for (int b = 0; b < 15; ++b) { off[b] = run; run += cnt[b]; }
  }
  __syncthreads();
  for (int q = tid; q < 2048; q += 1024) {
    int m = max(max(wlen[q * 4], wlen[q * 4 + 1]),
                max(wlen[q * 4 + 2], wlen[q * 4 + 3]));
    int pos = atomicAdd(&off[m - 1], 1);
    qorder[pos] = q;
  }
}

// ---------------------------------------------------------------------------
// xp_gemm (R13-measured, byte-identical): one block = 128 CONTIGUOUS rows
// (16 consecutive samples x 8 t) x FULL N=1536. A staged once in 133KB LDS;
// B (Wih bf16, 1.5MB) from L2. Grid (512, 2=dir). Biases folded. Dense
// sample-indexed stores.
// ---------------------------------------------------------------------------
#define LROWA 520  // LDS A row stride (bf16 elems)

__global__ __launch_bounds__(256)
__attribute__((amdgpu_waves_per_eu(1, 1))) void xp_gemm(
    const float* __restrict__ win, const int* __restrict__ wlen,
    const u16* __restrict__ Wihb_f, const u16* __restrict__ Wihb_b,
    const float* __restrict__ bih_f, const float* __restrict__ bih_b,
    const float* __restrict__ bhh_f, const float* __restrict__ bhh_b,
    u16* __restrict__ xp) {
  extern __shared__ char smem[];
  u16* As = (u16*)smem;  // [128][LROWA]

  const int dir = blockIdx.y;
  const u16* Wb = dir ? Wihb_b : Wihb_f;
  const float* bih = dir ? bih_b : bih_f;
  const float* bhh = dir ? bhh_b : bhh_f;

  const int tid = threadIdx.x;
  const int bx = blockIdx.x;

  // ---- stage A: 128 gathered rows (16 consecutive samples), f32 -> bf16 ----
  {
    const int r = tid >> 1, hh = tid & 1;
    const int m = bx * 128 + r;
    const int s = m >> 3, tt = m & 7;
    const int wl = wlen[s];
    const int len = dir ? (wl / 2 + 1) : ((wl - 1) / 2 + 1);
    const int widx = dir ? (6 + len - tt) : (8 - len + tt);  // in [0,14]
    const float* src = win + ((size_t)s * 15 + widx) * 512 + hh * 256;
    u16* dst = As + r * LROWA + hh * 256;
#pragma unroll
    for (int i = 0; i < 32; ++i) {
      f32x4 v0 = *(const f32x4*)(src + i * 8);
      f32x4 v1 = *(const f32x4*)(src + i * 8 + 4);
      u16x8 o;
      o[0] = f2bf(v0[0]); o[1] = f2bf(v0[1]); o[2] = f2bf(v0[2]); o[3] = f2bf(v0[3]);
      o[4] = f2bf(v1[0]); o[5] = f2bf(v1[1]); o[6] = f2bf(v1[2]); o[7] = f2bf(v1[3]);
      *(u16x8*)(dst + i * 8) = o;
    }
  }
  __syncthreads();

  const int wave = tid >> 6;
  const int lane = tid & 63;
  const int ln = lane & 15;
  const int ks = lane >> 4;

#pragma unroll 1
  for (int g = 0; g < 6; ++g) {
    const int c0 = wave * 24 + g * 4;

    f32x4 acc[8][4];
#pragma unroll
    for (int mt = 0; mt < 8; ++mt)
#pragma unroll
      for (int u = 0; u < 4; ++u)
#pragma unroll
        for (int j = 0; j < 4; ++j) acc[mt][u][j] = 0.f;

#pragma unroll
    for (int kk = 0; kk < 16; ++kk) {
      const int krel = kk * 32 + ks * 8;
      bf16x8 a[8];
#pragma unroll
      for (int mt = 0; mt < 8; ++mt)
        a[mt] = *(const bf16x8*)(As + (mt * 16 + ln) * LROWA + krel);
      bf16x8 b[4];
#pragma unroll
      for (int u = 0; u < 4; ++u)
        b[u] = *(const bf16x8*)(Wb + (size_t)((c0 + u) * 16 + ln) * 512 + krel);
#pragma unroll
      for (int mt = 0; mt < 8; ++mt)
#pragma unroll
        for (int u = 0; u < 4; ++u) acc[mt][u] = MFMA(a[mt], b[u], acc[mt][u]);
    }

    // epilogue: fold biases, store to sample-indexed xp layout
#pragma unroll
    for (int u = 0; u < 4; ++u) {
      const int col = (c0 + u) * 16 + ln;
      const float bv = bih[col] + (col < 1024 ? bhh[col] : 0.f);
#pragma unroll
      for (int mt = 0; mt < 8; ++mt)
#pragma unroll
        for (int j = 0; j < 4; ++j) {
          const int rowm = bx * 128 + mt * 16 + ks * 4 + j;
          const int s = rowm >> 3, t = rowm & 7;
          const size_t idx = ((size_t)(dir * 8 + t) * 96 + (c0 + u)) * GSTRIDE +
                             (size_t)(s >> 2) * 64 + ln * 4 + (s & 3);
          xp[idx] = f2bf(acc[mt][u][j] + bv);
        }
    }
  }
}

// ---------------------------------------------------------------------------
// gru_rec (R13 + quad-sort indirection): 256 blocks x 1024 threads. Each
// block owns 16 SORTED quads (64 samples) -> block bmax drops ~8 -> ~6.9
// (the isolated lever behind the sorted family's gru=895; xp_gemm stays
// untouched this time). xp prefetch reads whole 128B quad-lines via qord;
// hcat written via indirection (1KB rows); mlp needs no unpermute.
// ---------------------------------------------------------------------------
#define LROW 520  // padded LDS row stride (bf16) to break bank conflicts

__global__ __launch_bounds__(1024)
__attribute__((amdgpu_waves_per_eu(4, 4))) void gru_rec(
    const int* __restrict__ wlen, const int* __restrict__ qorder,
    const u16* __restrict__ Wp_f, const u16* __restrict__ Wp_b,
    const float* __restrict__ bhh_f, const float* __restrict__ bhh_b,
    const u16* __restrict__ xp, u16* __restrict__ hcat) {
  extern __shared__ char smem[];
  u16* hb0 = (u16*)smem;       // [64][LROW]
  u16* hb1 = hb0 + 64 * LROW;  // [64][LROW]
  int* len_s = (int*)(hb1 + 64 * LROW);  // [64]
  int* bmax_s = len_s + 64;
  int* qord_s = bmax_s + 1;  // [16]

  const int dir = blockIdx.x & 1;
  const int grp = blockIdx.x >> 1;
  const u16* W = dir ? Wp_b : Wp_f;
  const float* bhh = dir ? bhh_b : bhh_f;

  const int tid = threadIdx.x;
  const int wave = tid >> 6;  // 0..15
  const int lane = tid & 63;
  const int ln = lane & 15;
  const int ks = lane >> 4;  // 0..3

  // ---- init: zero hb0, quad ids, lengths + block max ----
  if (tid == 0) *bmax_s = 0;
  if (tid < 16) qord_s[tid] = qorder[grp * 16 + tid];
  for (int i = tid; i < 64 * LROW / 8; i += 1024) ((u16x8*)hb0)[i] = (u16x8)0;
  __syncthreads();
  if (tid < 64) {
    int sample = qord_s[tid >> 2] * 4 + (tid & 3);
    int wl = wlen[sample];
    int len = dir ? (wl / 2 + 1) : ((wl - 1) / 2 + 1);
    len_s[tid] = len;
    atomicMax(bmax_s, len);
  }
  __syncthreads();
  const int bmax = *bmax_s;

  // preload this thread's 4 quad ids (one per mt) into regs
  int qr[4];
#pragma unroll
  for (int mt = 0; mt < 4; ++mt) qr[mt] = qord_s[mt * 4 + ks];

  // only the n-gate recurrent bias survives (r,z biases folded into xp)
  float b_hn[2];
#pragma unroll
  for (int p = 0; p < 2; ++p) b_hn[p] = bhh[1024 + (p * 16 + wave) * 16 + ln];

  for (int t = 0; t < bmax; ++t) {
    u16* h_cur = (t & 1) ? hb1 : hb0;
    u16* h_nxt = (t & 1) ? hb0 : hb1;
    const u16* xpt = xp + (size_t)(dir * 8 + t) * 96 * GSTRIDE;

#pragma unroll
    for (int p = 0; p < 2; ++p) {
      const int q = p * 16 + wave;  // gate-col chunk 0..31
      const int dcol = q * 16 + ln;
      const u16* wq = W + (size_t)q * 24576 + lane * 8;  // fragment-ordered

      // ---- prefetch xp: 12 vector loads at quad-line granularity ----
      u16x4 xr4[4], xz4[4], xn4[4];
#pragma unroll
      for (int mt = 0; mt < 4; ++mt) {
        const size_t off = (size_t)qr[mt] * 64 + ln * 4;
        xr4[mt] = *(const u16x4*)(xpt + (size_t)q * GSTRIDE + off);
        xz4[mt] = *(const u16x4*)(xpt + (size_t)(32 + q) * GSTRIDE + off);
        xn4[mt] = *(const u16x4*)(xpt + (size_t)(64 + q) * GSTRIDE + off);
      }

      f32x4 accr[4], accz[4], acchn[4];
#pragma unroll
      for (int mt = 0; mt < 4; ++mt)
#pragma unroll
        for (int j = 0; j < 4; ++j) {
          accr[mt][j] = 0.f; accz[mt][j] = 0.f; acchn[mt][j] = 0.f;
        }

#pragma unroll
      for (int kk = 0; kk < 16; ++kk) {
        const int krel = kk * 32 + ks * 8;
        bf16x8 a[4];
#pragma unroll
        for (int mt = 0; mt < 4; ++mt)
          a[mt] = *(const bf16x8*)(h_cur + (mt * 16 + ln) * LROW + krel);
        const u16* wk = wq + kk * 1536;
        bf16x8 br = *(const bf16x8*)(wk);  // contiguous 1KB/wave
        bf16x8 bz = *(const bf16x8*)(wk + 512);
        bf16x8 bn = *(const bf16x8*)(wk + 1024);
#pragma unroll
        for (int mt = 0; mt < 4; ++mt) {
          accr[mt] = MFMA(a[mt], br, accr[mt]);
          accz[mt] = MFMA(a[mt], bz, accz[mt]);
          acchn[mt] = MFMA(a[mt], bn, acchn[mt]);
        }
      }

      // epilogue: prefetched xp + nonlinearity; write to the OTHER buffer
#pragma unroll
      for (int mt = 0; mt < 4; ++mt)
#pragma unroll
        for (int j = 0; j < 4; ++j) {
          const int row = mt * 16 + ks * 4 + j;
          float xr = bf2f(xr4[mt][j]);
          float xz = bf2f(xz4[mt][j]);
          float xn = bf2f(xn4[mt][j]);
          float rr = sigm(accr[mt][j] + xr);
          float zz = sigm(accz[mt][j] + xz);
          float nn = tanh_(xn + rr * (acchn[mt][j] + b_hn[p]));
          float hold = bf2f(h_cur[row * LROW + dcol]);
          float hnew = (t < len_s[row]) ? ((1.f - zz) * nn + zz * hold) : hold;
          h_nxt[row * LROW + dcol] = f2bf(hnew);
        }
    }  // passes
    __syncthreads();  // h_nxt complete before it becomes h_cur
  }    // t

  // ---- write final h to hcat[sample][dir*512 + k] via quad indirection ----
  const u16* hf = (bmax & 1) ? hb1 : hb0;
  const int xrow = tid >> 4;  // 0..63
  const int xseg = tid & 15;  // 0..15
  const int sample = qord_s[xrow >> 2] * 4 + (xrow & 3);
#pragma unroll
  for (int i = 0; i < 4; ++i) {
    int off = (i * 16 + xseg) * 8;
    u16x8 v = *(const u16x8*)(hf + xrow * LROW + off);
    __builtin_nontemporal_store(
        v, (u16x8*)(hcat + (size_t)sample * 1024 + dir * 512 + off));
  }
}

// ---------------------------------------------------------------------------
// FALLBACK path (ws too small): round-2 fused kernel.
// ---------------------------------------------------------------------------
__global__ __launch_bounds__(256) void build_wcat(const float* __restrict__ Whh,
                                                  const float* __restrict__ Wih,
                                                  u16* __restrict__ Wcat) {
  int i = blockIdx.x * 256 + threadIdx.x;
  if (i >= 1536 * 1024 / 8) return;
  int e = i * 8;
  int g = e >> 10, k = e & 1023;
  const float* src = (k < 512) ? (Whh + g * 512 + k) : (Wih + g * 512 + (k - 512));
  u16x8 o;
#pragma unroll
  for (int j = 0; j < 8; ++j) o[j] = f2bf(src[j]);
  *(u16x8*)(Wcat + e) = o;
}

__global__ __launch_bounds__(512)
__attribute__((amdgpu_waves_per_eu(2, 2))) void gru_persistent(
    const float* __restrict__ win, const int* __restrict__ wlen,
    const u16* __restrict__ Wcat_f, const u16* __restrict__ Wcat_b,
    const float* __restrict__ bih_f, const float* __restrict__ bhh_f,
    const float* __restrict__ bih_b, const float* __restrict__ bhh_b,
    u16* __restrict__ hcat) {
  extern __shared__ char smem[];
  u16* h_s = (u16*)smem;
  u16* x_s = (u16*)(smem + 64 * LROW * 2);
  int* len_s = (int*)(smem + 2 * 64 * LROW * 2);
  int* bmax_s = len_s + 64;

  const int dir = blockIdx.x & 1;
  const int grp = blockIdx.x >> 1;
  const int s0 = grp * 64;
  const u16* W = dir ? Wcat_b : Wcat_f;
  const float* bih = dir ? bih_b : bih_f;
  const float* bhh = dir ? bhh_b : bhh_f;

  const int tid = threadIdx.x;
  const int wave = tid >> 6;
  const int lane = tid & 63;
  const int ln = lane & 15;
  const int ks = lane >> 4;

  if (tid == 0) *bmax_s = 0;
  for (int i = tid; i < 64 * LROW / 8; i += 512) ((u16x8*)h_s)[i] = (u16x8)0;
  __syncthreads();
  if (tid < 64) {
    int wl = wlen[s0 + tid];
    int len = dir ? (wl / 2 + 1) : ((wl - 1) / 2 + 1);
    len_s[tid] = len;
    atomicMax(bmax_s, len);
  }
  __syncthreads();
  const int bmax = *bmax_s;

  float b_r[4], b_z[4], b_xn[4], b_hn[4];
#pragma unroll
  for (int p = 0; p < 4; ++p) {
    int d = (p * 8 + wave) * 16 + ln;
    b_r[p] = bih[d] + bhh[d];
    b_z[p] = bih[512 + d] + bhh[512 + d];
    b_xn[p] = bih[1024 + d];
    b_hn[p] = bhh[1024 + d];
  }

  const int xrow = tid >> 3;
  const int xcol = tid & 7;
  const int mylen = len_s[xrow];
  const long xbase = (long)(s0 + xrow) * 15 + (dir ? (6 + mylen) : (8 - mylen));

  for (int t = 0; t < bmax; ++t) {
    {
      long rowidx = dir ? (xbase - t) : (xbase + t);
      const float* src = win + rowidx * 512;
      u16* dst = x_s + xrow * LROW;
#pragma unroll
      for (int i = 0; i < 8; ++i) {
        int off = xcol * 8 + i * 64;
        f32x4 v0 = *(const f32x4*)(src + off);
        f32x4 v1 = *(const f32x4*)(src + off + 4);
        u16x8 o;
        o[0] = f2bf(v0[0]); o[1] = f2bf(v0[1]); o[2] = f2bf(v0[2]); o[3] = f2bf(v0[3]);
        o[4] = f2bf(v1[0]); o[5] = f2bf(v1[1]); o[6] = f2bf(v1[2]); o[7] = f2bf(v1[3]);
        *(u16x8*)(dst + off) = o;
      }
    }
    __syncthreads();

    unsigned holdp[3][4][2];

#pragma unroll
    for (int p = 0; p < 4; ++p) {
      const int dcol = (p * 8 + wave) * 16 + ln;
      const u16* wrow = W + (size_t)dcol * 1024;

      f32x4 accr[4], accz[4], acchn[4], accxn[4];
#pragma unroll
      for (int mt = 0; mt < 4; ++mt)
#pragma unroll
        for (int j = 0; j < 4; ++j) {
          accr[mt][j] = 0.f; accz[mt][j] = 0.f;
          acchn[mt][j] = 0.f; accxn[mt][j] = 0.f;
        }

#pragma unroll
      for (int kk = 0; kk < 16; ++kk) {
        const int krel = kk * 32 + ks * 8;
        bf16x8 a[4];
#pragma unroll
        for (int mt = 0; mt < 4; ++mt)
          a[mt] = *(const bf16x8*)(h_s + (mt * 16 + ln) * LROW + krel);
        bf16x8 br = *(const bf16x8*)(wrow + krel);
        bf16x8 bz = *(const bf16x8*)(wrow + 512 * 1024 + krel);
        bf16x8 bn = *(const bf16x8*)(wrow + 1024 * 1024 + krel);
#pragma unroll
        for (int mt = 0; mt < 4; ++mt) {
          accr[mt] = MFMA(a[mt], br, accr[mt]);
          accz[mt] = MFMA(a[mt], bz, accz[mt]);
          acchn[mt] = MFMA(a[mt], bn, acchn[mt]);
        }
      }
#pragma unroll
      for (int kk = 0; kk < 16; ++kk) {
        const int krel = kk * 32 + ks * 8;
        bf16x8 a[4];
#pragma unroll
        for (int mt = 0; mt < 4; ++mt)
          a[mt] = *(const bf16x8*)(x_s + (mt * 16 + ln) * LROW + krel);
        bf16x8 br = *(const bf16x8*)(wrow + 512 + krel);
        bf16x8 bz = *(const bf16x8*)(wrow + 512 * 1024 + 512 + krel);
        bf16x8 bn = *(const bf16x8*)(wrow + 1024 * 1024 + 512 + krel);
#pragma unroll
        for (int mt = 0; mt < 4; ++mt) {
          accr[mt] = MFMA(a[mt], br, accr[mt]);
          accz[mt] = MFMA(a[mt], bz, accz[mt]);
          accxn[mt] = MFMA(a[mt], bn, accxn[mt]);
        }
      }

      if (p < 3) {
#pragma unroll
        for (int mt = 0; mt < 4; ++mt)
#pragma unroll
          for (int jp = 0; jp < 2; ++jp) {
            unsigned pk = 0;
#pragma unroll
            for (int jh = 0; jh < 2; ++jh) {
              const int j = jp * 2 + jh;
              const int row = mt * 16 + ks * 4 + j;
              float rr = sigm(accr[mt][j] + b_r[p]);
              float zz = sigm(accz[mt][j] + b_z[p]);
              float nn = tanh_(accxn[mt][j] + b_xn[p] +
                               rr * (acchn[mt][j] + b_hn[p]));
              float hold = bf2f(h_s[row * LROW + dcol]);
              float hnew = (t < len_s[row]) ? ((1.f - zz) * nn + zz * hold) : hold;
              pk |= ((unsigned)f2bf(hnew)) << (16 * jh);
            }
            holdp[p][mt][jp] = pk;
          }
      } else {
        __syncthreads();
#pragma unroll
        for (int pp = 0; pp < 3; ++pp) {
          const int dd = (pp * 8 + wave) * 16 + ln;
#pragma unroll
          for (int mt = 0; mt < 4; ++mt)
#pragma unroll
            for (int jp = 0; jp < 2; ++jp) {
              unsigned pk = holdp[pp][mt][jp];
              const int row = mt * 16 + ks * 4 + jp * 2;
              h_s[row * LROW + dd] = (u16)pk;
              h_s[(row + 1) * LROW + dd] = (u16)(pk >> 16);
            }
        }
#pragma unroll
        for (int mt = 0; mt < 4; ++mt)
#pragma unroll
          for (int j = 0; j < 4; ++j) {
            const int row = mt * 16 + ks * 4 + j;
            float rr = sigm(accr[mt][j] + b_r[3]);
            float zz = sigm(accz[mt][j] + b_z[3]);
            float nn = tanh_(accxn[mt][j] + b_xn[3] +
                             rr * (acchn[mt][j] + b_hn[3]));
            float hold = bf2f(h_s[row * LROW + dcol]);
            float hnew = (t < len_s[row]) ? ((1.f - zz) * nn + zz * hold) : hold;
            h_s[row * LROW + dcol] = f2bf(hnew);
          }
      }
    }
  }

  __syncthreads();
#pragma unroll
  for (int i = 0; i < 8; ++i) {
    int off = xcol * 8 + i * 64;
    u16x8 v = *(const u16x8*)(h_s + xrow * LROW + off);
    __builtin_nontemporal_store(
        v, (u16x8*)(hcat + (size_t)(s0 + xrow) * 1024 + dir * 512 + off));
  }
}

// ---------------------------------------------------------------------------
// MLP GEMM: out[M,N] = act(A[M,K] @ Bw[N,K]^T + bias)
// ---------------------------------------------------------------------------
__global__ __launch_bounds__(256) void mlp_gemm(const u16* __restrict__ A,
                                                const u16* __restrict__ Bw,
                                                const float* __restrict__ bias,
                                                void* __restrict__ out, int M,
                                                int N, int K, int mode) {
  __shared__ u16 As[128 * 64], Bs[128 * 64];
  const int tid = threadIdx.x;
  const int wave = tid >> 6, lane = tid & 63;
  const int ln = lane & 15, ks = lane >> 4;
  const int wm = wave & 1, wn = wave >> 1;
  const int m0 = blockIdx.x * 128, n0 = blockIdx.y * 128;
  f32x4 acc[4][4];
#pragma unroll
  for (int mt = 0; mt < 4; ++mt)
#pragma unroll
    for (int nt = 0; nt < 4; ++nt)
#pragma unroll
      for (int j = 0; j < 4; ++j) acc[mt][nt][j] = 0.f;

  const int r = tid >> 1, hh = tid & 1;
  for (int k0 = 0; k0 < K; k0 += 64) {
    const i32x4* sa = (const i32x4*)(A + (size_t)(m0 + r) * K + k0 + hh * 32);
    const i32x4* sb = (const i32x4*)(Bw + (size_t)(n0 + r) * K + k0 + hh * 32);
    i32x4* da = (i32x4*)(As + r * 64 + hh * 32);
    i32x4* db = (i32x4*)(Bs + r * 64 + hh * 32);
#pragma unroll
    for (int i = 0; i < 4; ++i) da[i] = sa[i];
#pragma unroll
    for (int i = 0; i < 4; ++i) db[i] = sb[i];
    __syncthreads();
#pragma unroll
    for (int kk = 0; kk < 2; ++kk) {
      bf16x8 af[4], bfm[4];
#pragma unroll
      for (int mt = 0; mt < 4; ++mt)
        af[mt] = *(const bf16x8*)(As + (wm * 64 + mt * 16 + ln) * 64 + kk * 32 + ks * 8);
#pragma unroll
      for (int nt = 0; nt < 4; ++nt)
        bfm[nt] = *(const bf16x8*)(Bs + (wn * 64 + nt * 16 + ln) * 64 + kk * 32 + ks * 8);
#pragma unroll
      for (int mt = 0; mt < 4; ++mt)
#pragma unroll
        for (int nt = 0; nt < 4; ++nt) acc[mt][nt] = MFMA(af[mt], bfm[nt], acc[mt][nt]);
    }
    __syncthreads();
  }

#pragma unroll
  for (int nt = 0; nt < 4; ++nt) {
    int col = n0 + wn * 64 + nt * 16 + ln;
    float bv = bias[col];
#pragma unroll
    for (int mt = 0; mt < 4; ++mt)
#pragma unroll
      for (int j = 0; j < 4; ++j) {
        int row = m0 + wm * 64 + mt * 16 + ks * 4 + j;
        float v = acc[mt][nt][j] + bv;
        if (mode) {
          v = fmaxf(v, 0.f);
          ((u16*)out)[(size_t)row * N + col] = f2bf(v);
        } else {
          ((float*)out)[(size_t)row * N + col] = v;
        }
      }
  }
}

// ---------------------------------------------------------------------------
extern "C" void kernel_launch(void* const* d_in, const int* in_sizes, int n_in,
                              void* d_out, int out_size, void* d_ws, size_t ws_size,
                              hipStream_t stream) {
  (void)in_sizes; (void)n_in; (void)out_size;
  const float* win = (const float*)d_in[0];
  const int* wlen = (const int*)d_in[1];
  const float* Wih_f = (const float*)d_in[2];
  const float* Whh_f = (const float*)d_in[3];
  const float* bih_f = (const float*)d_in[4];
  const float* bhh_f = (const float*)d_in[5];
  const float* Wih_b = (const float*)d_in[6];
  const float* Whh_b = (const float*)d_in[7];
  const float* bih_b = (const float*)d_in[8];
  const float* bhh_b = (const float*)d_in[9];
  const float* W1 = (const float*)d_in[10];
  const float* b1 = (const float*)d_in[11];
  const float* W2 = (const float*)d_in[12];
  const float* b2 = (const float*)d_in[13];

  const size_t NEED = 4ull * 1572864 + 1048576 + 524288 + 16777216 + 8388608 +
                      402653184ull + 16384;  // +qorder

  if (ws_size >= NEED) {
    char* ws = (char*)d_ws;
    u16* Wp_f = (u16*)ws;   ws += 1572864;
    u16* Wp_b = (u16*)ws;   ws += 1572864;
    u16* Wihb_f = (u16*)ws; ws += 1572864;
    u16* Wihb_b = (u16*)ws; ws += 1572864;
    u16* W1b = (u16*)ws;    ws += 1048576;
    u16* W2b = (u16*)ws;    ws += 524288;
    u16* hcat = (u16*)ws;   ws += 16777216;
    u16* hidden = (u16*)ws; ws += 8388608;
    int* qorder = (int*)ws; ws += 16384;
    u16* xp = (u16*)ws;     ws += 402653184;

    sort_quads<<<1, 1024, 0, stream>>>(wlen, qorder);
    wrepack<<<384, 256, 0, stream>>>(Whh_f, Wp_f);
    wrepack<<<384, 256, 0, stream>>>(Whh_b, Wp_b);
    cvt_bf16<<<384, 256, 0, stream>>>(Wih_f, Wihb_f, 98304);
    cvt_bf16<<<384, 256, 0, stream>>>(Wih_b, Wihb_b, 98304);
    cvt_bf16<<<256, 256, 0, stream>>>(W1, W1b, 65536);
    cvt_bf16<<<128, 256, 0, stream>>>(W2, W2b, 32768);

    const int SMEM_XP = 128 * LROWA * 2;  // 133,120 B
    (void)hipFuncSetAttribute((const void*)xp_gemm,
                              hipFuncAttributeMaxDynamicSharedMemorySize, SMEM_XP);
    xp_gemm<<<dim3(512, 2), 256, SMEM_XP, stream>>>(
        win, wlen, Wihb_f, Wihb_b, bih_f, bih_b, bhh_f, bhh_b, xp);

    const int SMEM = 2 * 64 * LROW * 2 + 64 * 4 + 4 + 16 * 4 + 64;
    (void)hipFuncSetAttribute((const void*)gru_rec,
                              hipFuncAttributeMaxDynamicSharedMemorySize, SMEM);
    gru_rec<<<256, 1024, SMEM, stream>>>(wlen, qorder, Wp_f, Wp_b, bhh_f,
                                         bhh_b, xp, hcat);

    mlp_gemm<<<dim3(64, 4), 256, 0, stream>>>(hcat, W1b, b1, hidden, 8192, 512,
                                              1024, 1);
    mlp_gemm<<<dim3(64, 4), 256, 0, stream>>>(hidden, W2b, b2, d_out, 8192, 512,
                                              512, 0);
  } else {
    char* ws = (char*)d_ws;
    u16* Wcat_f = (u16*)ws;  ws += 3145728;
    u16* Wcat_b = (u16*)ws;  ws += 3145728;
    u16* W1b = (u16*)ws;     ws += 1048576;
    u16* W2b = (u16*)ws;     ws += 524288;
    u16* hcat = (u16*)ws;    ws += 16777216;
    u16* hidden = (u16*)ws;  ws += 8388608;

    build_wcat<<<768, 256, 0, stream>>>(Whh_f, Wih_f, Wcat_f);
    build_wcat<<<768, 256, 0, stream>>>(Whh_b, Wih_b, Wcat_b);
    cvt_bf16<<<256, 256, 0, stream>>>(W1, W1b, 65536);
    cvt_bf16<<<128, 256, 0, stream>>>(W2, W2b, 32768);

    const int SMEM = 2 * 64 * LROW * 2 + 64 * 4 + 16;
    (void)hipFuncSetAttribute((const void*)gru_persistent,
                              hipFuncAttributeMaxDynamicSharedMemorySize, SMEM);
    gru_persistent<<<256, 512, SMEM, stream>>>(win, wlen, Wcat_f, Wcat_b, bih_f,
                                               bhh_f, bih_b, bhh_b, hcat);

    mlp_gemm<<<dim3(64, 4), 256, 0, stream>>>(hcat, W1b, b1, hidden, 8192, 512,
                                              1024, 1);
    mlp_gemm<<<dim3(64, 4), 256, 0, stream>>>(hidden, W2b, b2, d_out, 8192, 512,
                                              512, 0);
  }
}

// Round 16
// 1770.325 us; speedup vs baseline: 3.4176x; 1.0144x over previous
//
#include <hip/hip_runtime.h>

typedef unsigned short u16;
typedef __attribute__((ext_vector_type(4))) float f32x4;
typedef __attribute__((ext_vector_type(8))) __bf16 bf16x8;
typedef __attribute__((ext_vector_type(8))) u16 u16x8;
typedef __attribute__((ext_vector_type(4))) u16 u16x4;
typedef __attribute__((ext_vector_type(4))) int i32x4;

#define MFMA(a, b, c) __builtin_amdgcn_mfma_f32_16x16x32_bf16(a, b, c, 0, 0, 0)

__device__ __forceinline__ u16 f2bf(float f) {
  union { float f; unsigned u; } v; v.f = f;
  unsigned r = v.u + 0x7FFFu + ((v.u >> 16) & 1u);
  return (u16)(r >> 16);
}
__device__ __forceinline__ float bf2f(u16 b) {
  union { unsigned u; float f; } v; v.u = ((unsigned)b) << 16; return v.f;
}
__device__ __forceinline__ float sigm(float x) { return 1.f / (1.f + __expf(-x)); }
__device__ __forceinline__ float tanh_(float x) {
  float e = __expf(-2.f * fabsf(x));
  float r = (1.f - e) / (1.f + e);
  return x < 0.f ? -r : r;
}

// xp layout (sample-indexed): plane = (dir*8 + t)*96 + g (g=col>>4).
// Within plane: offset = (s>>2)*64 + (col&15)*4 + (s&3). GSTRIDE elems/plane.
#define GSTRIDE 131072

// ---------------------------------------------------------------------------
__global__ __launch_bounds__(256) void cvt_bf16(const float* __restrict__ src,
                                                u16* __restrict__ dst, int n8) {
  int i = blockIdx.x * 256 + threadIdx.x;
  if (i >= n8) return;
  int e = i * 8;
  u16x8 o;
#pragma unroll
  for (int j = 0; j < 8; ++j) o[j] = f2bf(src[e + j]);
  *(u16x8*)(dst + e) = o;
}

// ---------------------------------------------------------------------------
// wrepack: Whh (f32 1536x512) -> fragment-ordered bf16 Wp (1KB contiguous
// per wave K-step load in gru_rec).
// ---------------------------------------------------------------------------
__global__ __launch_bounds__(256) void wrepack(const float* __restrict__ Whh,
                                               u16* __restrict__ Wp) {
  int i = blockIdx.x * 256 + threadIdx.x;  // one u16x8 per thread
  if (i >= 98304) return;
  int q = i / 3072;
  int r1 = i % 3072;
  int kk = r1 / 192;
  int r2 = r1 % 192;
  int g = r2 / 64;
  int r3 = r2 % 64;
  int ks = r3 >> 4, ln = r3 & 15;
  const float* src =
      Whh + (size_t)(g * 512 + q * 16 + ln) * 512 + kk * 32 + ks * 8;
  u16x8 o;
#pragma unroll
  for (int j = 0; j < 8; ++j) o[j] = f2bf(src[j]);
  *(u16x8*)(Wp + (size_t)i * 8) = o;
}

// ---------------------------------------------------------------------------
// sort_quads: counting-sort QUADS (4 consecutive samples) by max window_len.
// qorder[slot] = quad id. Quad granularity keeps xp's 128B quad-lines intact.
// ---------------------------------------------------------------------------
__global__ __launch_bounds__(1024) void sort_quads(const int* __restrict__ wlen,
                                                   int* __restrict__ qorder) {
  __shared__ int cnt[16];
  __shared__ int off[16];
  const int tid = threadIdx.x;
  if (tid < 16) cnt[tid] = 0;
  __syncthreads();
  for (int q = tid; q < 2048; q += 1024) {
    int m = max(max(wlen[q * 4], wlen[q * 4 + 1]),
                max(wlen[q * 4 + 2], wlen[q * 4 + 3]));
    atomicAdd(&cnt[m - 1], 1);
  }
  __syncthreads();
  if (tid == 0) {
    int run = 0;
#pragma unroll
    for (int b = 0; b < 15; ++b) { off[b] = run; run += cnt[b]; }
  }
  __syncthreads();
  for (int q = tid; q < 2048; q += 1024) {
    int m = max(max(wlen[q * 4], wlen[q * 4 + 1]),
                max(wlen[q * 4 + 2], wlen[q * 4 + 3]));
    int pos = atomicAdd(&off[m - 1], 1);
    qorder[pos] = q;
  }
}

// ---------------------------------------------------------------------------
// xp_gemm (round-15): R14's contiguous design at 512 THREADS (8 waves ->
// 2 waves/SIMD, was 1) -- the one untested occupancy lever on the one
// kernel with >=3x headroom (floor ~150us, measured ~500). Same 128-row
// contiguous tile (133KB LDS), same dense sample-indexed stores. Each wave:
// 12 n-chunks in 3 groups of 4, full M=128. acc 128 AGPR + ~80 VGPR fits
// the 256-reg 2-wv/SIMD budget. Biases bih (+bhh for r,z) folded.
// ---------------------------------------------------------------------------
#define LROWA 520  // LDS A row stride (bf16 elems)

__global__ __launch_bounds__(512)
__attribute__((amdgpu_waves_per_eu(2, 2))) void xp_gemm(
    const float* __restrict__ win, const int* __restrict__ wlen,
    const u16* __restrict__ Wihb_f, const u16* __restrict__ Wihb_b,
    const float* __restrict__ bih_f, const float* __restrict__ bih_b,
    const float* __restrict__ bhh_f, const float* __restrict__ bhh_b,
    u16* __restrict__ xp) {
  extern __shared__ char smem[];
  u16* As = (u16*)smem;  // [128][LROWA]

  const int dir = blockIdx.y;
  const u16* Wb = dir ? Wihb_b : Wihb_f;
  const float* bih = dir ? bih_b : bih_f;
  const float* bhh = dir ? bhh_b : bhh_f;

  const int tid = threadIdx.x;
  const int bx = blockIdx.x;

  // ---- stage A: 128 gathered rows (16 consecutive samples), f32 -> bf16 ----
  {
    const int r = tid >> 2, qq = tid & 3;  // 4 threads/row, 128 elems each
    const int m = bx * 128 + r;
    const int s = m >> 3, tt = m & 7;
    const int wl = wlen[s];
    const int len = dir ? (wl / 2 + 1) : ((wl - 1) / 2 + 1);
    const int widx = dir ? (6 + len - tt) : (8 - len + tt);  // in [0,14]
    const float* src = win + ((size_t)s * 15 + widx) * 512 + qq * 128;
    u16* dst = As + r * LROWA + qq * 128;
#pragma unroll
    for (int i = 0; i < 16; ++i) {
      f32x4 v0 = *(const f32x4*)(src + i * 8);
      f32x4 v1 = *(const f32x4*)(src + i * 8 + 4);
      u16x8 o;
      o[0] = f2bf(v0[0]); o[1] = f2bf(v0[1]); o[2] = f2bf(v0[2]); o[3] = f2bf(v0[3]);
      o[4] = f2bf(v1[0]); o[5] = f2bf(v1[1]); o[6] = f2bf(v1[2]); o[7] = f2bf(v1[3]);
      *(u16x8*)(dst + i * 8) = o;
    }
  }
  __syncthreads();

  const int wave = tid >> 6;  // 0..7
  const int lane = tid & 63;
  const int ln = lane & 15;
  const int ks = lane >> 4;

#pragma unroll 1
  for (int g = 0; g < 3; ++g) {
    const int c0 = wave * 12 + g * 4;  // 4 n-chunks per group

    f32x4 acc[8][4];
#pragma unroll
    for (int mt = 0; mt < 8; ++mt)
#pragma unroll
      for (int u = 0; u < 4; ++u)
#pragma unroll
        for (int j = 0; j < 4; ++j) acc[mt][u][j] = 0.f;

#pragma unroll
    for (int kk = 0; kk < 16; ++kk) {
      const int krel = kk * 32 + ks * 8;
      bf16x8 a[8];
#pragma unroll
      for (int mt = 0; mt < 8; ++mt)
        a[mt] = *(const bf16x8*)(As + (mt * 16 + ln) * LROWA + krel);
      bf16x8 b[4];
#pragma unroll
      for (int u = 0; u < 4; ++u)
        b[u] = *(const bf16x8*)(Wb + (size_t)((c0 + u) * 16 + ln) * 512 + krel);
#pragma unroll
      for (int mt = 0; mt < 8; ++mt)
#pragma unroll
        for (int u = 0; u < 4; ++u) acc[mt][u] = MFMA(a[mt], b[u], acc[mt][u]);
    }

    // epilogue: fold biases, store to sample-indexed xp layout
#pragma unroll
    for (int u = 0; u < 4; ++u) {
      const int col = (c0 + u) * 16 + ln;
      const float bv = bih[col] + (col < 1024 ? bhh[col] : 0.f);
#pragma unroll
      for (int mt = 0; mt < 8; ++mt)
#pragma unroll
        for (int j = 0; j < 4; ++j) {
          const int rowm = bx * 128 + mt * 16 + ks * 4 + j;
          const int s = rowm >> 3, t = rowm & 7;
          const size_t idx = ((size_t)(dir * 8 + t) * 96 + (c0 + u)) * GSTRIDE +
                             (size_t)(s >> 2) * 64 + ln * 4 + (s & 3);
          xp[idx] = f2bf(acc[mt][u][j] + bv);
        }
    }
  }
}

// ---------------------------------------------------------------------------
// gru_rec (R14-measured 1072us, unchanged): quad-sorted blocks, fragment-
// ordered Wp, h double-buffered, ONE barrier/step, quad-line xp prefetch.
// ---------------------------------------------------------------------------
#define LROW 520  // padded LDS row stride (bf16) to break bank conflicts

__global__ __launch_bounds__(1024)
__attribute__((amdgpu_waves_per_eu(4, 4))) void gru_rec(
    const int* __restrict__ wlen, const int* __restrict__ qorder,
    const u16* __restrict__ Wp_f, const u16* __restrict__ Wp_b,
    const float* __restrict__ bhh_f, const float* __restrict__ bhh_b,
    const u16* __restrict__ xp, u16* __restrict__ hcat) {
  extern __shared__ char smem[];
  u16* hb0 = (u16*)smem;       // [64][LROW]
  u16* hb1 = hb0 + 64 * LROW;  // [64][LROW]
  int* len_s = (int*)(hb1 + 64 * LROW);  // [64]
  int* bmax_s = len_s + 64;
  int* qord_s = bmax_s + 1;  // [16]

  const int dir = blockIdx.x & 1;
  const int grp = blockIdx.x >> 1;
  const u16* W = dir ? Wp_b : Wp_f;
  const float* bhh = dir ? bhh_b : bhh_f;

  const int tid = threadIdx.x;
  const int wave = tid >> 6;  // 0..15
  const int lane = tid & 63;
  const int ln = lane & 15;
  const int ks = lane >> 4;  // 0..3

  // ---- init: zero hb0, quad ids, lengths + block max ----
  if (tid == 0) *bmax_s = 0;
  if (tid < 16) qord_s[tid] = qorder[grp * 16 + tid];
  for (int i = tid; i < 64 * LROW / 8; i += 1024) ((u16x8*)hb0)[i] = (u16x8)0;
  __syncthreads();
  if (tid < 64) {
    int sample = qord_s[tid >> 2] * 4 + (tid & 3);
    int wl = wlen[sample];
    int len = dir ? (wl / 2 + 1) : ((wl - 1) / 2 + 1);
    len_s[tid] = len;
    atomicMax(bmax_s, len);
  }
  __syncthreads();
  const int bmax = *bmax_s;

  // preload this thread's 4 quad ids (one per mt) into regs
  int qr[4];
#pragma unroll
  for (int mt = 0; mt < 4; ++mt) qr[mt] = qord_s[mt * 4 + ks];

  // only the n-gate recurrent bias survives (r,z biases folded into xp)
  float b_hn[2];
#pragma unroll
  for (int p = 0; p < 2; ++p) b_hn[p] = bhh[1024 + (p * 16 + wave) * 16 + ln];

  for (int t = 0; t < bmax; ++t) {
    u16* h_cur = (t & 1) ? hb1 : hb0;
    u16* h_nxt = (t & 1) ? hb0 : hb1;
    const u16* xpt = xp + (size_t)(dir * 8 + t) * 96 * GSTRIDE;

#pragma unroll
    for (int p = 0; p < 2; ++p) {
      const int q = p * 16 + wave;  // gate-col chunk 0..31
      const int dcol = q * 16 + ln;
      const u16* wq = W + (size_t)q * 24576 + lane * 8;  // fragment-ordered

      // ---- prefetch xp: 12 vector loads at quad-line granularity ----
      u16x4 xr4[4], xz4[4], xn4[4];
#pragma unroll
      for (int mt = 0; mt < 4; ++mt) {
        const size_t off = (size_t)qr[mt] * 64 + ln * 4;
        xr4[mt] = *(const u16x4*)(xpt + (size_t)q * GSTRIDE + off);
        xz4[mt] = *(const u16x4*)(xpt + (size_t)(32 + q) * GSTRIDE + off);
        xn4[mt] = *(const u16x4*)(xpt + (size_t)(64 + q) * GSTRIDE + off);
      }

      f32x4 accr[4], accz[4], acchn[4];
#pragma unroll
      for (int mt = 0; mt < 4; ++mt)
#pragma unroll
        for (int j = 0; j < 4; ++j) {
          accr[mt][j] = 0.f; accz[mt][j] = 0.f; acchn[mt][j] = 0.f;
        }

#pragma unroll
      for (int kk = 0; kk < 16; ++kk) {
        const int krel = kk * 32 + ks * 8;
        bf16x8 a[4];
#pragma unroll
        for (int mt = 0; mt < 4; ++mt)
          a[mt] = *(const bf16x8*)(h_cur + (mt * 16 + ln) * LROW + krel);
        const u16* wk = wq + kk * 1536;
        bf16x8 br = *(const bf16x8*)(wk);  // contiguous 1KB/wave
        bf16x8 bz = *(const bf16x8*)(wk + 512);
        bf16x8 bn = *(const bf16x8*)(wk + 1024);
#pragma unroll
        for (int mt = 0; mt < 4; ++mt) {
          accr[mt] = MFMA(a[mt], br, accr[mt]);
          accz[mt] = MFMA(a[mt], bz, accz[mt]);
          acchn[mt] = MFMA(a[mt], bn, acchn[mt]);
        }
      }

      // epilogue: prefetched xp + nonlinearity; write to the OTHER buffer
#pragma unroll
      for (int mt = 0; mt < 4; ++mt)
#pragma unroll
        for (int j = 0; j < 4; ++j) {
          const int row = mt * 16 + ks * 4 + j;
          float xr = bf2f(xr4[mt][j]);
          float xz = bf2f(xz4[mt][j]);
          float xn = bf2f(xn4[mt][j]);
          float rr = sigm(accr[mt][j] + xr);
          float zz = sigm(accz[mt][j] + xz);
          float nn = tanh_(xn + rr * (acchn[mt][j] + b_hn[p]));
          float hold = bf2f(h_cur[row * LROW + dcol]);
          float hnew = (t < len_s[row]) ? ((1.f - zz) * nn + zz * hold) : hold;
          h_nxt[row * LROW + dcol] = f2bf(hnew);
        }
    }  // passes
    __syncthreads();  // h_nxt complete before it becomes h_cur
  }    // t

  // ---- write final h to hcat[sample][dir*512 + k] via quad indirection ----
  const u16* hf = (bmax & 1) ? hb1 : hb0;
  const int xrow = tid >> 4;  // 0..63
  const int xseg = tid & 15;  // 0..15
  const int sample = qord_s[xrow >> 2] * 4 + (xrow & 3);
#pragma unroll
  for (int i = 0; i < 4; ++i) {
    int off = (i * 16 + xseg) * 8;
    u16x8 v = *(const u16x8*)(hf + xrow * LROW + off);
    __builtin_nontemporal_store(
        v, (u16x8*)(hcat + (size_t)sample * 1024 + dir * 512 + off));
  }
}

// ---------------------------------------------------------------------------
// FALLBACK path (ws too small): round-2 fused kernel.
// ---------------------------------------------------------------------------
__global__ __launch_bounds__(256) void build_wcat(const float* __restrict__ Whh,
                                                  const float* __restrict__ Wih,
                                                  u16* __restrict__ Wcat) {
  int i = blockIdx.x * 256 + threadIdx.x;
  if (i >= 1536 * 1024 / 8) return;
  int e = i * 8;
  int g = e >> 10, k = e & 1023;
  const float* src = (k < 512) ? (Whh + g * 512 + k) : (Wih + g * 512 + (k - 512));
  u16x8 o;
#pragma unroll
  for (int j = 0; j < 8; ++j) o[j] = f2bf(src[j]);
  *(u16x8*)(Wcat + e) = o;
}

__global__ __launch_bounds__(512)
__attribute__((amdgpu_waves_per_eu(2, 2))) void gru_persistent(
    const float* __restrict__ win, const int* __restrict__ wlen,
    const u16* __restrict__ Wcat_f, const u16* __restrict__ Wcat_b,
    const float* __restrict__ bih_f, const float* __restrict__ bhh_f,
    const float* __restrict__ bih_b, const float* __restrict__ bhh_b,
    u16* __restrict__ hcat) {
  extern __shared__ char smem[];
  u16* h_s = (u16*)smem;
  u16* x_s = (u16*)(smem + 64 * LROW * 2);
  int* len_s = (int*)(smem + 2 * 64 * LROW * 2);
  int* bmax_s = len_s + 64;

  const int dir = blockIdx.x & 1;
  const int grp = blockIdx.x >> 1;
  const int s0 = grp * 64;
  const u16* W = dir ? Wcat_b : Wcat_f;
  const float* bih = dir ? bih_b : bih_f;
  const float* bhh = dir ? bhh_b : bhh_f;

  const int tid = threadIdx.x;
  const int wave = tid >> 6;
  const int lane = tid & 63;
  const int ln = lane & 15;
  const int ks = lane >> 4;

  if (tid == 0) *bmax_s = 0;
  for (int i = tid; i < 64 * LROW / 8; i += 512) ((u16x8*)h_s)[i] = (u16x8)0;
  __syncthreads();
  if (tid < 64) {
    int wl = wlen[s0 + tid];
    int len = dir ? (wl / 2 + 1) : ((wl - 1) / 2 + 1);
    len_s[tid] = len;
    atomicMax(bmax_s, len);
  }
  __syncthreads();
  const int bmax = *bmax_s;

  float b_r[4], b_z[4], b_xn[4], b_hn[4];
#pragma unroll
  for (int p = 0; p < 4; ++p) {
    int d = (p * 8 + wave) * 16 + ln;
    b_r[p] = bih[d] + bhh[d];
    b_z[p] = bih[512 + d] + bhh[512 + d];
    b_xn[p] = bih[1024 + d];
    b_hn[p] = bhh[1024 + d];
  }

  const int xrow = tid >> 3;
  const int xcol = tid & 7;
  const int mylen = len_s[xrow];
  const long xbase = (long)(s0 + xrow) * 15 + (dir ? (6 + mylen) : (8 - mylen));

  for (int t = 0; t < bmax; ++t) {
    {
      long rowidx = dir ? (xbase - t) : (xbase + t);
      const float* src = win + rowidx * 512;
      u16* dst = x_s + xrow * LROW;
#pragma unroll
      for (int i = 0; i < 8; ++i) {
        int off = xcol * 8 + i * 64;
        f32x4 v0 = *(const f32x4*)(src + off);
        f32x4 v1 = *(const f32x4*)(src + off + 4);
        u16x8 o;
        o[0] = f2bf(v0[0]); o[1] = f2bf(v0[1]); o[2] = f2bf(v0[2]); o[3] = f2bf(v0[3]);
        o[4] = f2bf(v1[0]); o[5] = f2bf(v1[1]); o[6] = f2bf(v1[2]); o[7] = f2bf(v1[3]);
        *(u16x8*)(dst + off) = o;
      }
    }
    __syncthreads();

    unsigned holdp[3][4][2];

#pragma unroll
    for (int p = 0; p < 4; ++p) {
      const int dcol = (p * 8 + wave) * 16 + ln;
      const u16* wrow = W + (size_t)dcol * 1024;

      f32x4 accr[4], accz[4], acchn[4], accxn[4];
#pragma unroll
      for (int mt = 0; mt < 4; ++mt)
#pragma unroll
        for (int j = 0; j < 4; ++j) {
          accr[mt][j] = 0.f; accz[mt][j] = 0.f;
          acchn[mt][j] = 0.f; accxn[mt][j] = 0.f;
        }

#pragma unroll
      for (int kk = 0; kk < 16; ++kk) {
        const int krel = kk * 32 + ks * 8;
        bf16x8 a[4];
#pragma unroll
        for (int mt = 0; mt < 4; ++mt)
          a[mt] = *(const bf16x8*)(h_s + (mt * 16 + ln) * LROW + krel);
        bf16x8 br = *(const bf16x8*)(wrow + krel);
        bf16x8 bz = *(const bf16x8*)(wrow + 512 * 1024 + krel);
        bf16x8 bn = *(const bf16x8*)(wrow + 1024 * 1024 + krel);
#pragma unroll
        for (int mt = 0; mt < 4; ++mt) {
          accr[mt] = MFMA(a[mt], br, accr[mt]);
          accz[mt] = MFMA(a[mt], bz, accz[mt]);
          acchn[mt] = MFMA(a[mt], bn, acchn[mt]);
        }
      }
#pragma unroll
      for (int kk = 0; kk < 16; ++kk) {
        const int krel = kk * 32 + ks * 8;
        bf16x8 a[4];
#pragma unroll
        for (int mt = 0; mt < 4; ++mt)
          a[mt] = *(const bf16x8*)(x_s + (mt * 16 + ln) * LROW + krel);
        bf16x8 br = *(const bf16x8*)(wrow + 512 + krel);
        bf16x8 bz = *(const bf16x8*)(wrow + 512 * 1024 + 512 + krel);
        bf16x8 bn = *(const bf16x8*)(wrow + 1024 * 1024 + 512 + krel);
#pragma unroll
        for (int mt = 0; mt < 4; ++mt) {
          accr[mt] = MFMA(a[mt], br, accr[mt]);
          accz[mt] = MFMA(a[mt], bz, accz[mt]);
          accxn[mt] = MFMA(a[mt], bn, accxn[mt]);
        }
      }

      if (p < 3) {
#pragma unroll
        for (int mt = 0; mt < 4; ++mt)
#pragma unroll
          for (int jp = 0; jp < 2; ++jp) {
            unsigned pk = 0;
#pragma unroll
            for (int jh = 0; jh < 2; ++jh) {
              const int j = jp * 2 + jh;
              const int row = mt * 16 + ks * 4 + j;
              float rr = sigm(accr[mt][j] + b_r[p]);
              float zz = sigm(accz[mt][j] + b_z[p]);
              float nn = tanh_(accxn[mt][j] + b_xn[p] +
                               rr * (acchn[mt][j] + b_hn[p]));
              float hold = bf2f(h_s[row * LROW + dcol]);
              float hnew = (t < len_s[row]) ? ((1.f - zz) * nn + zz * hold) : hold;
              pk |= ((unsigned)f2bf(hnew)) << (16 * jh);
            }
            holdp[p][mt][jp] = pk;
          }
      } else {
        __syncthreads();
#pragma unroll
        for (int pp = 0; pp < 3; ++pp) {
          const int dd = (pp * 8 + wave) * 16 + ln;
#pragma unroll
          for (int mt = 0; mt < 4; ++mt)
#pragma unroll
            for (int jp = 0; jp < 2; ++jp) {
              unsigned pk = holdp[pp][mt][jp];
              const int row = mt * 16 + ks * 4 + jp * 2;
              h_s[row * LROW + dd] = (u16)pk;
              h_s[(row + 1) * LROW + dd] = (u16)(pk >> 16);
            }
        }
#pragma unroll
        for (int mt = 0; mt < 4; ++mt)
#pragma unroll
          for (int j = 0; j < 4; ++j) {
            const int row = mt * 16 + ks * 4 + j;
            float rr = sigm(accr[mt][j] + b_r[3]);
            float zz = sigm(accz[mt][j] + b_z[3]);
            float nn = tanh_(accxn[mt][j] + b_xn[3] +
                             rr * (acchn[mt][j] + b_hn[3]));
            float hold = bf2f(h_s[row * LROW + dcol]);
            float hnew = (t < len_s[row]) ? ((1.f - zz) * nn + zz * hold) : hold;
            h_s[row * LROW + dcol] = f2bf(hnew);
          }
      }
    }
  }

  __syncthreads();
#pragma unroll
  for (int i = 0; i < 8; ++i) {
    int off = xcol * 8 + i * 64;
    u16x8 v = *(const u16x8*)(h_s + xrow * LROW + off);
    __builtin_nontemporal_store(
        v, (u16x8*)(hcat + (size_t)(s0 + xrow) * 1024 + dir * 512 + off));
  }
}

// ---------------------------------------------------------------------------
// MLP GEMM: out[M,N] = act(A[M,K] @ Bw[N,K]^T + bias)
// ---------------------------------------------------------------------------
__global__ __launch_bounds__(256) void mlp_gemm(const u16* __restrict__ A,
                                                const u16* __restrict__ Bw,
                                                const float* __restrict__ bias,
                                                void* __restrict__ out, int M,
                                                int N, int K, int mode) {
  __shared__ u16 As[128 * 64], Bs[128 * 64];
  const int tid = threadIdx.x;
  const int wave = tid >> 6, lane = tid & 63;
  const int ln = lane & 15, ks = lane >> 4;
  const int wm = wave & 1, wn = wave >> 1;
  const int m0 = blockIdx.x * 128, n0 = blockIdx.y * 128;
  f32x4 acc[4][4];
#pragma unroll
  for (int mt = 0; mt < 4; ++mt)
#pragma unroll
    for (int nt = 0; nt < 4; ++nt)
#pragma unroll
      for (int j = 0; j < 4; ++j) acc[mt][nt][j] = 0.f;

  const int r = tid >> 1, hh = tid & 1;
  for (int k0 = 0; k0 < K; k0 += 64) {
    const i32x4* sa = (const i32x4*)(A + (size_t)(m0 + r) * K + k0 + hh * 32);
    const i32x4* sb = (const i32x4*)(Bw + (size_t)(n0 + r) * K + k0 + hh * 32);
    i32x4* da = (i32x4*)(As + r * 64 + hh * 32);
    i32x4* db = (i32x4*)(Bs + r * 64 + hh * 32);
#pragma unroll
    for (int i = 0; i < 4; ++i) da[i] = sa[i];
#pragma unroll
    for (int i = 0; i < 4; ++i) db[i] = sb[i];
    __syncthreads();
#pragma unroll
    for (int kk = 0; kk < 2; ++kk) {
      bf16x8 af[4], bfm[4];
#pragma unroll
      for (int mt = 0; mt < 4; ++mt)
        af[mt] = *(const bf16x8*)(As + (wm * 64 + mt * 16 + ln) * 64 + kk * 32 + ks * 8);
#pragma unroll
      for (int nt = 0; nt < 4; ++nt)
        bfm[nt] = *(const bf16x8*)(Bs + (wn * 64 + nt * 16 + ln) * 64 + kk * 32 + ks * 8);
#pragma unroll
      for (int mt = 0; mt < 4; ++mt)
#pragma unroll
        for (int nt = 0; nt < 4; ++nt) acc[mt][nt] = MFMA(af[mt], bfm[nt], acc[mt][nt]);
    }
    __syncthreads();
  }

#pragma unroll
  for (int nt = 0; nt < 4; ++nt) {
    int col = n0 + wn * 64 + nt * 16 + ln;
    float bv = bias[col];
#pragma unroll
    for (int mt = 0; mt < 4; ++mt)
#pragma unroll
      for (int j = 0; j < 4; ++j) {
        int row = m0 + wm * 64 + mt * 16 + ks * 4 + j;
        float v = acc[mt][nt][j] + bv;
        if (mode) {
          v = fmaxf(v, 0.f);
          ((u16*)out)[(size_t)row * N + col] = f2bf(v);
        } else {
          ((float*)out)[(size_t)row * N + col] = v;
        }
      }
  }
}

// ---------------------------------------------------------------------------
extern "C" void kernel_launch(void* const* d_in, const int* in_sizes, int n_in,
                              void* d_out, int out_size, void* d_ws, size_t ws_size,
                              hipStream_t stream) {
  (void)in_sizes; (void)n_in; (void)out_size;
  const float* win = (const float*)d_in[0];
  const int* wlen = (const int*)d_in[1];
  const float* Wih_f = (const float*)d_in[2];
  const float* Whh_f = (const float*)d_in[3];
  const float* bih_f = (const float*)d_in[4];
  const float* bhh_f = (const float*)d_in[5];
  const float* Wih_b = (const float*)d_in[6];
  const float* Whh_b = (const float*)d_in[7];
  const float* bih_b = (const float*)d_in[8];
  const float* bhh_b = (const float*)d_in[9];
  const float* W1 = (const float*)d_in[10];
  const float* b1 = (const float*)d_in[11];
  const float* W2 = (const float*)d_in[12];
  const float* b2 = (const float*)d_in[13];

  const size_t NEED = 4ull * 1572864 + 1048576 + 524288 + 16777216 + 8388608 +
                      402653184ull + 16384;  // +qorder

  if (ws_size >= NEED) {
    char* ws = (char*)d_ws;
    u16* Wp_f = (u16*)ws;   ws += 1572864;
    u16* Wp_b = (u16*)ws;   ws += 1572864;
    u16* Wihb_f = (u16*)ws; ws += 1572864;
    u16* Wihb_b = (u16*)ws; ws += 1572864;
    u16* W1b = (u16*)ws;    ws += 1048576;
    u16* W2b = (u16*)ws;    ws += 524288;
    u16* hcat = (u16*)ws;   ws += 16777216;
    u16* hidden = (u16*)ws; ws += 8388608;
    int* qorder = (int*)ws; ws += 16384;
    u16* xp = (u16*)ws;     ws += 402653184;

    sort_quads<<<1, 1024, 0, stream>>>(wlen, qorder);
    wrepack<<<384, 256, 0, stream>>>(Whh_f, Wp_f);
    wrepack<<<384, 256, 0, stream>>>(Whh_b, Wp_b);
    cvt_bf16<<<384, 256, 0, stream>>>(Wih_f, Wihb_f, 98304);
    cvt_bf16<<<384, 256, 0, stream>>>(Wih_b, Wihb_b, 98304);
    cvt_bf16<<<256, 256, 0, stream>>>(W1, W1b, 65536);
    cvt_bf16<<<128, 256, 0, stream>>>(W2, W2b, 32768);

    const int SMEM_XP = 128 * LROWA * 2;  // 133,120 B
    (void)hipFuncSetAttribute((const void*)xp_gemm,
                              hipFuncAttributeMaxDynamicSharedMemorySize, SMEM_XP);
    xp_gemm<<<dim3(512, 2), 512, SMEM_XP, stream>>>(
        win, wlen, Wihb_f, Wihb_b, bih_f, bih_b, bhh_f, bhh_b, xp);

    const int SMEM = 2 * 64 * LROW * 2 + 64 * 4 + 4 + 16 * 4 + 64;
    (void)hipFuncSetAttribute((const void*)gru_rec,
                              hipFuncAttributeMaxDynamicSharedMemorySize, SMEM);
    gru_rec<<<256, 1024, SMEM, stream>>>(wlen, qorder, Wp_f, Wp_b, bhh_f,
                                         bhh_b, xp, hcat);

    mlp_gemm<<<dim3(64, 4), 256, 0, stream>>>(hcat, W1b, b1, hidden, 8192, 512,
                                              1024, 1);
    mlp_gemm<<<dim3(64, 4), 256, 0, stream>>>(hidden, W2b, b2, d_out, 8192, 512,
                                              512, 0);
  } else {
    char* ws = (char*)d_ws;
    u16* Wcat_f = (u16*)ws;  ws += 3145728;
    u16* Wcat_b = (u16*)ws;  ws += 3145728;
    u16* W1b = (u16*)ws;     ws += 1048576;
    u16* W2b = (u16*)ws;     ws += 524288;
    u16* hcat = (u16*)ws;    ws += 16777216;
    u16* hidden = (u16*)ws;  ws += 8388608;

    build_wcat<<<768, 256, 0, stream>>>(Whh_f, Wih_f, Wcat_f);
    build_wcat<<<768, 256, 0, stream>>>(Whh_b, Wih_b, Wcat_b);
    cvt_bf16<<<256, 256, 0, stream>>>(W1, W1b, 65536);
    cvt_bf16<<<128, 256, 0, stream>>>(W2, W2b, 32768);

    const int SMEM = 2 * 64 * LROW * 2 + 64 * 4 + 16;
    (void)hipFuncSetAttribute((const void*)gru_persistent,
                              hipFuncAttributeMaxDynamicSharedMemorySize, SMEM);
    gru_persistent<<<256, 512, SMEM, stream>>>(win, wlen, Wcat_f, Wcat_b, bih_f,
                                               bhh_f, bih_b, bhh_b, hcat);

    mlp_gemm<<<dim3(64, 4), 256, 0, stream>>>(hcat, W1b, b1, hidden, 8192, 512,
                                              1024, 1);
    mlp_gemm<<<dim3(64, 4), 256, 0, stream>>>(hidden, W2b, b2, d_out, 8192, 512,
                                              512, 0);
  }
}